// Round 4
// baseline (215.441 us; speedup 1.0000x reference)
//
#include <hip/hip_runtime.h>

#define NEGF -3.402823466e38f
#define MASKED_F -3.38953139e38f   // bf16 0xFF7F, most-negative finite bf16

typedef __attribute__((ext_vector_type(8))) short bf16x8;
typedef __attribute__((ext_vector_type(4))) float f32x4;
typedef __attribute__((ext_vector_type(4))) unsigned short u16x4;

__device__ __forceinline__ unsigned short f2bf(float f) {
  unsigned u = __builtin_bit_cast(unsigned, f);
  u += 0x7fffu + ((u >> 16) & 1u);
  return (unsigned short)(u >> 16);
}

// ws layout in ushort units
#define OFF_QH  0u
#define OFF_KH  2097152u
#define OFF_W   4194304u      // 4 x 65536 (Wq,Wk,Wv,Wo)
#define OFF_QP  4456448u      // [B,H,S,D] bf16, pre-scaled by 1/8
#define OFF_KP  6553600u      // [B,H,S,D] bf16
#define OFF_VT  8650752u      // [B,H,D,S] bf16 (V transposed)
#define OFF_ATT 10747904u     // [B,S,256] bf16
#define OFF_M   12845056u     // [B][128][32][64][16] bf16 fragment-ordered combined mask (32 MB)
#define USHORT_USED 29622272u // end of OFF_M region

// ---------------- f32 -> bf16 conversion of inputs ----------------
__global__ __launch_bounds__(256) void k_convert(
    const float* __restrict__ qh, const float* __restrict__ kh,
    const float* __restrict__ w0, const float* __restrict__ w1,
    const float* __restrict__ w2, const float* __restrict__ w3,
    unsigned short* __restrict__ dst) {
  int v = blockIdx.x * 256 + threadIdx.x;   // vector-of-4 index
  const float* src;
  if (v < 524288)       src = qh + (size_t)v * 4;
  else if (v < 1048576) src = kh + ((size_t)v - 524288) * 4;
  else {
    int t = v - 1048576;                    // 0 .. 65535
    int which = t >> 14;
    const float* w = (which == 0) ? w0 : (which == 1) ? w1 : (which == 2) ? w2 : w3;
    src = w + (size_t)(t & 16383) * 4;
  }
  f32x4 x = *(const f32x4*)src;
  u16x4 o;
  o[0] = f2bf(x[0]); o[1] = f2bf(x[1]); o[2] = f2bf(x[2]); o[3] = f2bf(x[3]);
  *(u16x4*)(dst + (size_t)v * 4) = o;
}

// ---------------- combined-mask prepass ----------------
__global__ __launch_bounds__(256) void k_maskprep(const float* __restrict__ am,
    const int* __restrict__ al, unsigned short* __restrict__ M) {
  __shared__ float L[64 * 65];
  int bid = blockIdx.x;
  int b = bid >> 10, q64 = (bid >> 5) & 31, k64 = bid & 31;
  int t = threadIdx.x, c = t & 63, rg = t >> 6;

  const float* amb = am + ((size_t)b * 2048 + q64 * 64) * 2048 + k64 * 64;
#pragma unroll
  for (int i = 0; i < 16; ++i) {
    int row = i * 4 + rg;
    L[row * 65 + c] = amb[(size_t)row * 2048 + c];
  }
  __syncthreads();
  const int* alb = al + ((size_t)b * 2048 + k64 * 64) * 2048 + q64 * 64;
#pragma unroll
  for (int i = 0; i < 16; ++i) {
    int kr = i * 4 + rg;
    if (alb[(size_t)kr * 2048 + c] == 0) L[c * 65 + kr] = MASKED_F;
  }
  __syncthreads();
  int w = t >> 6, lane = t & 63, l15 = lane & 15, l4 = lane >> 4;
  unsigned short* outp = M + ((((size_t)(b * 128 + q64 * 4 + w)) * 32 + k64) * 64 + lane) * 16;
#pragma unroll
  for (int kt = 0; kt < 4; ++kt) {
    u16x4 o;
#pragma unroll
    for (int r = 0; r < 4; ++r)
      o[r] = f2bf(L[(w * 16 + l4 * 4 + r) * 65 + kt * 16 + l15]);
    *(u16x4*)(outp + kt * 4) = o;
  }
}

// ---------------- QKV projections ----------------
__global__ __launch_bounds__(256) void k_proj(unsigned short* __restrict__ ws) {
  int bid = blockIdx.x;
  int mat = bid / 512;            // 0=Q 1=K 2=V
  int rem = bid - mat * 512;
  int mt = rem >> 2, nt = rem & 3;
  int tid = threadIdx.x, w = tid >> 6, lane = tid & 63;
  int l15 = lane & 15, l4 = lane >> 4;

  const unsigned short* X = ws + (mat == 0 ? OFF_QH : OFF_KH);
  const unsigned short* W = ws + OFF_W + (size_t)mat * 65536;

  int i0 = mt * 64 + w * 16;
  int arow = i0 + l15;
  int koff = l4 * 8;

  f32x4 acc[4] = {};
  for (int ks = 0; ks < 8; ++ks) {
    bf16x8 a = *(const bf16x8*)(X + (size_t)arow * 256 + ks * 32 + koff);
#pragma unroll
    for (int ct = 0; ct < 4; ++ct) {
      bf16x8 bb = *(const bf16x8*)(W + (size_t)(nt * 64 + ct * 16 + l15) * 256 + ks * 32 + koff);
      acc[ct] = __builtin_amdgcn_mfma_f32_16x16x32_bf16(a, bb, acc[ct], 0, 0, 0);
    }
  }

  unsigned short* Qp = ws + OFF_QP;
  unsigned short* Kp = ws + OFF_KP;
  unsigned short* Vt = ws + OFF_VT;
  int rbase = i0 + l4 * 4;
#pragma unroll
  for (int ct = 0; ct < 4; ++ct) {
#pragma unroll
    for (int r = 0; r < 4; ++r) {
      int row = rbase + r;
      int b = row >> 11, s = row & 2047;
      int d = ct * 16 + l15;
      float v = acc[ct][r];
      if (mat == 0)      Qp[((size_t)(b * 4 + nt) * 2048 + s) * 64 + d] = f2bf(v * 0.125f);
      else if (mat == 1) Kp[((size_t)(b * 4 + nt) * 2048 + s) * 64 + d] = f2bf(v);
      else               Vt[((size_t)(b * 4 + nt) * 64 + d) * 2048 + s] = f2bf(v);
    }
  }
}

// ---------------- fused masked flash attention (K-split) ----------------
// writes unnormalized O + (m,l) partials per split to f32 workspace
template <int NS>
__global__ __launch_bounds__(256) void k_attn(unsigned short* __restrict__ ws,
    float* __restrict__ po, float* __restrict__ pm, float* __restrict__ pl) {
  constexpr int LOG = (NS == 4) ? 2 : (NS == 2) ? 1 : 0;
  constexpr int SPAN = 2048 / NS;

  __shared__ __align__(16) unsigned short plds[4][1024];  // per-wave 16x64 bf16, XOR-swizzled

  int bid = blockIdx.x;
  int sp = bid & (NS - 1);
  int qt = (bid >> LOG) & 31;
  int bh = bid >> (LOG + 5);
  int tid = threadIdx.x, w = tid >> 6, lane = tid & 63;
  int l15 = lane & 15, l4 = lane >> 4;
  int q0 = qt * 64 + w * 16;        // this wave's 16 q rows

  const unsigned short* Qp = ws + OFF_QP;
  const unsigned short* Kp = ws + OFF_KP;
  const unsigned short* Vt = ws + OFF_VT;
  int b = bh >> 2;
  const unsigned short* Mw = ws + OFF_M +
      (((size_t)(b * 128 + qt * 4 + w)) * 32) * 1024 + (size_t)lane * 16;

  bf16x8 qf0 = *(const bf16x8*)(Qp + ((size_t)bh * 2048 + q0 + l15) * 64 + l4 * 8);
  bf16x8 qf1 = *(const bf16x8*)(Qp + ((size_t)bh * 2048 + q0 + l15) * 64 + 32 + l4 * 8);

  f32x4 o[4] = {};
  float mrun[4] = {-__builtin_inff(), -__builtin_inff(), -__builtin_inff(), -__builtin_inff()};
  float lrun[4] = {0.f, 0.f, 0.f, 0.f};

  for (int kk = sp * SPAN; kk < sp * SPAN + SPAN; kk += 64) {
    // ---- mask fragment loads (32 B / lane, contiguous; k-tile stride = 1024) ----
    const unsigned short* mp = Mw + ((size_t)(kk >> 6)) * 1024;
    bf16x8 m0 = *(const bf16x8*)mp;
    bf16x8 m1 = *(const bf16x8*)(mp + 8);
    // ---- scores: S = (Q/8) @ K^T  (16 x 64 per wave) ----
    f32x4 sfr[4];
#pragma unroll
    for (int kt = 0; kt < 4; ++kt) {
      const unsigned short* kp = Kp + ((size_t)bh * 2048 + kk + kt * 16 + l15) * 64 + l4 * 8;
      bf16x8 k0 = *(const bf16x8*)kp;
      bf16x8 k1 = *(const bf16x8*)(kp + 32);
      f32x4 acc = {};
      acc = __builtin_amdgcn_mfma_f32_16x16x32_bf16(qf0, k0, acc, 0, 0, 0);
      acc = __builtin_amdgcn_mfma_f32_16x16x32_bf16(qf1, k1, acc, 0, 0, 0);
      sfr[kt] = acc;
    }
    // ---- apply combined mask ----
#pragma unroll
    for (int kt = 0; kt < 4; ++kt) {
#pragma unroll
      for (int r = 0; r < 4; ++r) {
        int j = kt * 4 + r;
        unsigned short mu = (unsigned short)(j < 8 ? m0[j] : m1[j & 7]);
        float madd = __builtin_bit_cast(float, (unsigned)mu << 16);
        sfr[kt][r] = fmaxf(sfr[kt][r] + madd, NEGF);
      }
    }
    // ---- online softmax ----
    float mnew[4], sfac[4];
#pragma unroll
    for (int r = 0; r < 4; ++r) {
      float rm = fmaxf(fmaxf(sfr[0][r], sfr[1][r]), fmaxf(sfr[2][r], sfr[3][r]));
      rm = fmaxf(rm, __shfl_xor(rm, 1));
      rm = fmaxf(rm, __shfl_xor(rm, 2));
      rm = fmaxf(rm, __shfl_xor(rm, 4));
      rm = fmaxf(rm, __shfl_xor(rm, 8));
      mnew[r] = fmaxf(mrun[r], rm);
      sfac[r] = __expf(mrun[r] - mnew[r]);
      mrun[r] = mnew[r];
    }
#pragma unroll
    for (int kt = 0; kt < 4; ++kt)
#pragma unroll
      for (int r = 0; r < 4; ++r)
        sfr[kt][r] = __expf(sfr[kt][r] - mnew[r]);
#pragma unroll
    for (int r = 0; r < 4; ++r) {
      float rs = sfr[0][r] + sfr[1][r] + sfr[2][r] + sfr[3][r];
      rs += __shfl_xor(rs, 1);
      rs += __shfl_xor(rs, 2);
      rs += __shfl_xor(rs, 4);
      rs += __shfl_xor(rs, 8);
      lrun[r] = lrun[r] * sfac[r] + rs;
      o[0][r] *= sfac[r]; o[1][r] *= sfac[r]; o[2][r] *= sfac[r]; o[3][r] *= sfac[r];
    }
    // ---- P (C-layout) -> LDS (XOR-swizzled) -> A-layout fragments ----
#pragma unroll
    for (int kt = 0; kt < 4; ++kt)
#pragma unroll
      for (int r = 0; r < 4; ++r) {
        int prow = l4 * 4 + r;
        int pcol = kt * 16 + l15;
        plds[w][prow * 64 + (((pcol >> 3) ^ (prow & 7)) << 3) + (pcol & 7)] = f2bf(sfr[kt][r]);
      }
    // ---- PV: O += P @ V ----
#pragma unroll
    for (int ks = 0; ks < 2; ++ks) {
      int chnk = ks * 4 + l4;
      bf16x8 pa = *(const bf16x8*)&plds[w][l15 * 64 + ((chnk ^ (l15 & 7)) << 3)];
#pragma unroll
      for (int dt = 0; dt < 4; ++dt) {
        const unsigned short* vp = Vt + ((size_t)bh * 64 + dt * 16 + l15) * 2048 + kk + ks * 32 + l4 * 8;
        bf16x8 vf = *(const bf16x8*)vp;
        o[dt] = __builtin_amdgcn_mfma_f32_16x16x32_bf16(pa, vf, o[dt], 0, 0, 0);
      }
    }
  }

  // ---- write partials ----
  float* pob = po + (((size_t)sp * 16 + bh) * 2048) * 64;
#pragma unroll
  for (int r = 0; r < 4; ++r) {
    int qrow = q0 + l4 * 4 + r;
#pragma unroll
    for (int dt = 0; dt < 4; ++dt)
      pob[(size_t)qrow * 64 + dt * 16 + l15] = o[dt][r];
    if (l15 == 0) {
      pm[(size_t)sp * 32768 + bh * 2048 + qrow] = mrun[r];
      pl[(size_t)sp * 32768 + bh * 2048 + qrow] = lrun[r];
    }
  }
}

// ---------------- combine K-splits ----------------
template <int NS>
__global__ __launch_bounds__(256) void k_combine(const float* __restrict__ po,
    const float* __restrict__ pm, const float* __restrict__ pl,
    unsigned short* __restrict__ attnb) {
  int t = blockIdx.x * 256 + threadIdx.x;
  int d = t & 63;
  int row = t >> 6;                 // bh*2048 + qrow, 0..32767

  float m[NS], l[NS];
  float M = -__builtin_inff();
#pragma unroll
  for (int sp = 0; sp < NS; ++sp) {
    m[sp] = pm[(size_t)sp * 32768 + row];
    l[sp] = pl[(size_t)sp * 32768 + row];
    M = fmaxf(M, m[sp]);
  }
  float denom = 0.f, acc = 0.f;
#pragma unroll
  for (int sp = 0; sp < NS; ++sp) {
    float wgt = __expf(m[sp] - M);
    denom += l[sp] * wgt;
    acc += po[((size_t)sp * 32768 + row) * 64 + d] * wgt;
  }
  float val = acc / denom;
  int bh = row >> 11, qrow = row & 2047;
  int b = bh >> 2, h = bh & 3;
  attnb[((size_t)(b * 2048 + qrow)) * 256 + h * 64 + d] = f2bf(val);
}

// ---------------- output projection ----------------
__global__ __launch_bounds__(256) void k_oproj(const unsigned short* __restrict__ ws,
                                               float* __restrict__ out) {
  int bid = blockIdx.x;
  int mt = bid >> 2, nt = bid & 3;
  int tid = threadIdx.x, w = tid >> 6, lane = tid & 63;
  int l15 = lane & 15, l4 = lane >> 4;

  const unsigned short* A = ws + OFF_ATT;
  const unsigned short* W = ws + OFF_W + 3u * 65536u;   // Wo
  int i0 = mt * 64 + w * 16;

  f32x4 acc[4] = {};
  for (int ks = 0; ks < 8; ++ks) {
    bf16x8 a = *(const bf16x8*)(A + (size_t)(i0 + l15) * 256 + ks * 32 + l4 * 8);
#pragma unroll
    for (int ct = 0; ct < 4; ++ct) {
      bf16x8 bb = *(const bf16x8*)(W + (size_t)(nt * 64 + ct * 16 + l15) * 256 + ks * 32 + l4 * 8);
      acc[ct] = __builtin_amdgcn_mfma_f32_16x16x32_bf16(a, bb, acc[ct], 0, 0, 0);
    }
  }
#pragma unroll
  for (int ct = 0; ct < 4; ++ct)
#pragma unroll
    for (int r = 0; r < 4; ++r)
      out[(size_t)(i0 + l4 * 4 + r) * 256 + nt * 64 + ct * 16 + l15] = acc[ct][r];
}

extern "C" void kernel_launch(void* const* d_in, const int* in_sizes, int n_in,
                              void* d_out, int out_size, void* d_ws, size_t ws_size,
                              hipStream_t stream) {
  const float* qh = (const float*)d_in[0];
  const float* kh = (const float*)d_in[1];
  const float* amask = (const float*)d_in[2];
  const int* alignm = (const int*)d_in[3];
  const float* Wq = (const float*)d_in[4];
  const float* Wk = (const float*)d_in[5];
  const float* Wv = (const float*)d_in[6];
  const float* Wo = (const float*)d_in[7];
  float* out = (float*)d_out;
  unsigned short* ws = (unsigned short*)d_ws;

  k_convert<<<4352, 256, 0, stream>>>(qh, kh, Wq, Wk, Wv, Wo, ws);
  k_maskprep<<<4096, 256, 0, stream>>>(amask, alignm, ws + OFF_M);
  k_proj<<<1536, 256, 0, stream>>>(ws);

  // f32 partial buffers after the mask region; pick largest NS that fits ws
  size_t avail_f = (ws_size > (size_t)USHORT_USED * 2)
                       ? (ws_size - (size_t)USHORT_USED * 2) / 4 : 0;
  auto need = [](int ns) { return (size_t)ns * (2097152 + 65536); };
  int NSv = (avail_f >= need(4)) ? 4 : (avail_f >= need(2)) ? 2 : 1;
  float* po = (float*)(ws + USHORT_USED);
  float* pm = po + (size_t)NSv * 2097152;
  float* pl = pm + (size_t)NSv * 32768;

  if (NSv == 4) {
    k_attn<4><<<2048, 256, 0, stream>>>(ws, po, pm, pl);
    k_combine<4><<<8192, 256, 0, stream>>>(po, pm, pl, ws + OFF_ATT);
  } else if (NSv == 2) {
    k_attn<2><<<1024, 256, 0, stream>>>(ws, po, pm, pl);
    k_combine<2><<<8192, 256, 0, stream>>>(po, pm, pl, ws + OFF_ATT);
  } else {
    k_attn<1><<<512, 256, 0, stream>>>(ws, po, pm, pl);
    k_combine<1><<<8192, 256, 0, stream>>>(po, pm, pl, ws + OFF_ATT);
  }
  k_oproj<<<512, 256, 0, stream>>>(ws, out);
}

// Round 5
// 152.916 us; speedup vs baseline: 1.4089x; 1.4089x over previous
//
#include <hip/hip_runtime.h>

#define NEGF -3.402823466e38f
#define MASKED_F -3.38953139e38f   // bf16 0xFF7F, most-negative finite bf16

typedef __attribute__((ext_vector_type(8))) short bf16x8;
typedef __attribute__((ext_vector_type(4))) float f32x4;
typedef __attribute__((ext_vector_type(4))) unsigned short u16x4;

__device__ __forceinline__ unsigned short f2bf(float f) {
  unsigned u = __builtin_bit_cast(unsigned, f);
  u += 0x7fffu + ((u >> 16) & 1u);
  return (unsigned short)(u >> 16);
}

#define GLOAD_LDS16(gsrc, ldst)                                                     \
  __builtin_amdgcn_global_load_lds(                                                 \
      (const __attribute__((address_space(1))) void*)(gsrc),                        \
      (__attribute__((address_space(3))) void*)(ldst), 16, 0, 0)

// ws layout in ushort units
#define OFF_QH  0u
#define OFF_KH  2097152u
#define OFF_W   4194304u      // 4 x 65536 (Wq,Wk,Wv,Wo)
#define OFF_QP  4456448u      // [B,H,S,D] bf16, pre-scaled by 1/8
#define OFF_KP  6553600u      // [B,H,S,D] bf16
#define OFF_VT  8650752u      // [B,H,D,S] bf16 (V transposed)
#define OFF_ATT 10747904u     // [B,S,256] bf16
#define OFF_M   12845056u     // [B][128][32][64][16] bf16 fragment-ordered combined mask (32 MB)

// ---------------- f32 -> bf16 conversion of inputs ----------------
__global__ __launch_bounds__(256) void k_convert(
    const float* __restrict__ qh, const float* __restrict__ kh,
    const float* __restrict__ w0, const float* __restrict__ w1,
    const float* __restrict__ w2, const float* __restrict__ w3,
    unsigned short* __restrict__ dst) {
  int v = blockIdx.x * 256 + threadIdx.x;   // vector-of-4 index
  const float* src;
  if (v < 524288)       src = qh + (size_t)v * 4;
  else if (v < 1048576) src = kh + ((size_t)v - 524288) * 4;
  else {
    int t = v - 1048576;                    // 0 .. 65535
    int which = t >> 14;
    const float* w = (which == 0) ? w0 : (which == 1) ? w1 : (which == 2) ? w2 : w3;
    src = w + (size_t)(t & 16383) * 4;
  }
  f32x4 x = *(const f32x4*)src;
  u16x4 o;
  o[0] = f2bf(x[0]); o[1] = f2bf(x[1]); o[2] = f2bf(x[2]); o[3] = f2bf(x[3]);
  *(u16x4*)(dst + (size_t)v * 4) = o;
}

// ---------------- combined-mask prepass ----------------
__global__ __launch_bounds__(256) void k_maskprep(const float* __restrict__ am,
    const int* __restrict__ al, unsigned short* __restrict__ M) {
  __shared__ float L[64 * 65];
  int bid = blockIdx.x;
  int b = bid >> 10, q64 = (bid >> 5) & 31, k64 = bid & 31;
  int t = threadIdx.x, c = t & 63, rg = t >> 6;

  const float* amb = am + ((size_t)b * 2048 + q64 * 64) * 2048 + k64 * 64;
#pragma unroll
  for (int i = 0; i < 16; ++i) {
    int row = i * 4 + rg;
    L[row * 65 + c] = amb[(size_t)row * 2048 + c];
  }
  __syncthreads();
  const int* alb = al + ((size_t)b * 2048 + k64 * 64) * 2048 + q64 * 64;
#pragma unroll
  for (int i = 0; i < 16; ++i) {
    int kr = i * 4 + rg;
    if (alb[(size_t)kr * 2048 + c] == 0) L[c * 65 + kr] = MASKED_F;
  }
  __syncthreads();
  int w = t >> 6, lane = t & 63, l15 = lane & 15, l4 = lane >> 4;
  unsigned short* outp = M + ((((size_t)(b * 128 + q64 * 4 + w)) * 32 + k64) * 64 + lane) * 16;
#pragma unroll
  for (int kt = 0; kt < 4; ++kt) {
    u16x4 o;
#pragma unroll
    for (int r = 0; r < 4; ++r)
      o[r] = f2bf(L[(w * 16 + l4 * 4 + r) * 65 + kt * 16 + l15]);
    *(u16x4*)(outp + kt * 4) = o;
  }
}

// ---------------- QKV projections ----------------
__global__ __launch_bounds__(256) void k_proj(unsigned short* __restrict__ ws) {
  int bid = blockIdx.x;
  int mat = bid / 512;            // 0=Q 1=K 2=V
  int rem = bid - mat * 512;
  int mt = rem >> 2, nt = rem & 3;
  int tid = threadIdx.x, w = tid >> 6, lane = tid & 63;
  int l15 = lane & 15, l4 = lane >> 4;

  const unsigned short* X = ws + (mat == 0 ? OFF_QH : OFF_KH);
  const unsigned short* W = ws + OFF_W + (size_t)mat * 65536;

  int i0 = mt * 64 + w * 16;
  int arow = i0 + l15;
  int koff = l4 * 8;

  f32x4 acc[4] = {};
  for (int ks = 0; ks < 8; ++ks) {
    bf16x8 a = *(const bf16x8*)(X + (size_t)arow * 256 + ks * 32 + koff);
#pragma unroll
    for (int ct = 0; ct < 4; ++ct) {
      bf16x8 bb = *(const bf16x8*)(W + (size_t)(nt * 64 + ct * 16 + l15) * 256 + ks * 32 + koff);
      acc[ct] = __builtin_amdgcn_mfma_f32_16x16x32_bf16(a, bb, acc[ct], 0, 0, 0);
    }
  }

  unsigned short* Qp = ws + OFF_QP;
  unsigned short* Kp = ws + OFF_KP;
  unsigned short* Vt = ws + OFF_VT;
  int rbase = i0 + l4 * 4;
#pragma unroll
  for (int ct = 0; ct < 4; ++ct) {
#pragma unroll
    for (int r = 0; r < 4; ++r) {
      int row = rbase + r;
      int b = row >> 11, s = row & 2047;
      int d = ct * 16 + l15;
      float v = acc[ct][r];
      if (mat == 0)      Qp[((size_t)(b * 4 + nt) * 2048 + s) * 64 + d] = f2bf(v * 0.125f);
      else if (mat == 1) Kp[((size_t)(b * 4 + nt) * 2048 + s) * 64 + d] = f2bf(v);
      else               Vt[((size_t)(b * 4 + nt) * 64 + d) * 2048 + s] = f2bf(v);
    }
  }
}

// ---------------- fused masked flash attention (LDS-staged K/V, 2-phase) ----------------
// LDS tiles are XOR-swizzled: LDS(row, chunk c) holds global (row, c ^ (row&7)),
// chunks are 8 ushorts (16B). Staged via global_load_lds with inverse-swizzled
// per-lane GLOBAL source (rule: both-sides-or-neither).
__global__ __launch_bounds__(256) void k_attn(unsigned short* __restrict__ ws) {
  __shared__ __align__(16) unsigned short Kb[2][4096];   // [64 krow][64 d] swizzled
  __shared__ __align__(16) unsigned short Vb[2][4096];   // [64 d][64 k] swizzled
  __shared__ __align__(16) unsigned short plds[4][1024]; // per-wave 16x64 P, swizzled

  int bh = blockIdx.x >> 5, qt = blockIdx.x & 31;
  int b = bh >> 2, h = bh & 3;
  int tid = threadIdx.x, w = tid >> 6, lane = tid & 63;
  int l15 = lane & 15, l4 = lane >> 4;
  int q0 = qt * 64 + w * 16;

  const unsigned short* Qp = ws + OFF_QP;
  const unsigned short* Kp = ws + OFF_KP + (size_t)bh * 2048 * 64;
  const unsigned short* Vt = ws + OFF_VT + (size_t)bh * 64 * 2048;
  const unsigned short* Mw = ws + OFF_M +
      (((size_t)(b * 128 + qt * 4 + w)) * 32) * 1024 + (size_t)lane * 16;

  // staging geometry: lane i covers row (chunkbase + i>>3), global col chunk (i&7)^(i>>3)
  int srow = lane >> 3;
  int scol = ((lane & 7) ^ srow) * 8;
  int c0 = w * 2;                       // this wave's two 8-row chunks

  bf16x8 qf0 = *(const bf16x8*)(Qp + ((size_t)bh * 2048 + q0 + l15) * 64 + l4 * 8);
  bf16x8 qf1 = *(const bf16x8*)(Qp + ((size_t)bh * 2048 + q0 + l15) * 64 + 32 + l4 * 8);

  f32x4 o[4] = {};
  float mrun[4] = {-__builtin_inff(), -__builtin_inff(), -__builtin_inff(), -__builtin_inff()};
  float lrun[4] = {0.f, 0.f, 0.f, 0.f};

  // prologue: stage tile 0 into buffer 0
#pragma unroll
  for (int c2 = 0; c2 < 2; ++c2) {
    int c = c0 + c2;
    GLOAD_LDS16(Kp + (size_t)(c * 8 + srow) * 64 + scol, &Kb[0][c * 512]);
    GLOAD_LDS16(Vt + (size_t)(c * 8 + srow) * 2048 + scol, &Vb[0][c * 512]);
  }
  __syncthreads();

  int cur = 0;
  for (int kk = 0; kk < 2048; kk += 64) {
    // ---- stage next tile into the other buffer ----
    if (kk + 64 < 2048) {
#pragma unroll
      for (int c2 = 0; c2 < 2; ++c2) {
        int c = c0 + c2;
        GLOAD_LDS16(Kp + (size_t)(kk + 64 + c * 8 + srow) * 64 + scol, &Kb[cur ^ 1][c * 512]);
        GLOAD_LDS16(Vt + (size_t)(c * 8 + srow) * 2048 + (kk + 64) + scol, &Vb[cur ^ 1][c * 512]);
      }
    }
    // ---- mask fragment loads (32 B / lane contiguous) ----
    const unsigned short* mp = Mw + ((size_t)(kk >> 6)) * 1024;
    bf16x8 m0 = *(const bf16x8*)mp;
    bf16x8 m1 = *(const bf16x8*)(mp + 8);

    // ---- scores: S = (Q/8) @ K^T from LDS ----
    f32x4 sfr[4];
    __builtin_amdgcn_s_setprio(1);
#pragma unroll
    for (int kt = 0; kt < 4; ++kt) {
      int row = kt * 16 + l15;
      int sw = l15 & 7;
      bf16x8 k0 = *(const bf16x8*)&Kb[cur][row * 64 + ((l4 ^ sw) * 8)];
      bf16x8 k1 = *(const bf16x8*)&Kb[cur][row * 64 + (((4 + l4) ^ sw) * 8)];
      f32x4 acc = {};
      acc = __builtin_amdgcn_mfma_f32_16x16x32_bf16(qf0, k0, acc, 0, 0, 0);
      acc = __builtin_amdgcn_mfma_f32_16x16x32_bf16(qf1, k1, acc, 0, 0, 0);
      sfr[kt] = acc;
    }
    __builtin_amdgcn_s_setprio(0);

    // ---- apply combined mask ----
#pragma unroll
    for (int kt = 0; kt < 4; ++kt) {
#pragma unroll
      for (int r = 0; r < 4; ++r) {
        int j = kt * 4 + r;
        unsigned short mu = (unsigned short)(j < 8 ? m0[j] : m1[j & 7]);
        float madd = __builtin_bit_cast(float, (unsigned)mu << 16);
        sfr[kt][r] = fmaxf(sfr[kt][r] + madd, NEGF);
      }
    }
    // ---- online softmax ----
    float mnew[4], sfac[4];
#pragma unroll
    for (int r = 0; r < 4; ++r) {
      float rm = fmaxf(fmaxf(sfr[0][r], sfr[1][r]), fmaxf(sfr[2][r], sfr[3][r]));
      rm = fmaxf(rm, __shfl_xor(rm, 1));
      rm = fmaxf(rm, __shfl_xor(rm, 2));
      rm = fmaxf(rm, __shfl_xor(rm, 4));
      rm = fmaxf(rm, __shfl_xor(rm, 8));
      mnew[r] = fmaxf(mrun[r], rm);
      sfac[r] = __expf(mrun[r] - mnew[r]);
      mrun[r] = mnew[r];
    }
#pragma unroll
    for (int kt = 0; kt < 4; ++kt)
#pragma unroll
      for (int r = 0; r < 4; ++r)
        sfr[kt][r] = __expf(sfr[kt][r] - mnew[r]);
#pragma unroll
    for (int r = 0; r < 4; ++r) {
      float rs = sfr[0][r] + sfr[1][r] + sfr[2][r] + sfr[3][r];
      rs += __shfl_xor(rs, 1);
      rs += __shfl_xor(rs, 2);
      rs += __shfl_xor(rs, 4);
      rs += __shfl_xor(rs, 8);
      lrun[r] = lrun[r] * sfac[r] + rs;
      o[0][r] *= sfac[r]; o[1][r] *= sfac[r]; o[2][r] *= sfac[r]; o[3][r] *= sfac[r];
    }
    // ---- P (C-layout) -> plds (XOR-swizzled) -> A-layout fragments ----
#pragma unroll
    for (int kt = 0; kt < 4; ++kt)
#pragma unroll
      for (int r = 0; r < 4; ++r) {
        int prow = l4 * 4 + r;
        int pcol = kt * 16 + l15;
        plds[w][prow * 64 + (((pcol >> 3) ^ (prow & 7)) << 3) + (pcol & 7)] = f2bf(sfr[kt][r]);
      }
    // ---- PV: O += P @ V from LDS ----
    __builtin_amdgcn_s_setprio(1);
#pragma unroll
    for (int ks = 0; ks < 2; ++ks) {
      int chnk = ks * 4 + l4;
      bf16x8 pa = *(const bf16x8*)&plds[w][l15 * 64 + ((chnk ^ (l15 & 7)) << 3)];
#pragma unroll
      for (int dt = 0; dt < 4; ++dt) {
        int row = dt * 16 + l15;
        bf16x8 vf = *(const bf16x8*)&Vb[cur][row * 64 + (((ks * 4 + l4) ^ (l15 & 7)) * 8)];
        o[dt] = __builtin_amdgcn_mfma_f32_16x16x32_bf16(pa, vf, o[dt], 0, 0, 0);
      }
    }
    __builtin_amdgcn_s_setprio(0);

    __syncthreads();   // drains vmcnt (stage done) + guards buffer swap
    cur ^= 1;
  }

  unsigned short* attnb = ws + OFF_ATT;
#pragma unroll
  for (int r = 0; r < 4; ++r) {
    float inv = 1.0f / lrun[r];
    int qrow = q0 + l4 * 4 + r;
#pragma unroll
    for (int dt = 0; dt < 4; ++dt)
      attnb[(size_t)(b * 2048 + qrow) * 256 + h * 64 + dt * 16 + l15] = f2bf(o[dt][r] * inv);
  }
}

// ---------------- output projection ----------------
__global__ __launch_bounds__(256) void k_oproj(const unsigned short* __restrict__ ws,
                                               float* __restrict__ out) {
  int bid = blockIdx.x;
  int mt = bid >> 2, nt = bid & 3;
  int tid = threadIdx.x, w = tid >> 6, lane = tid & 63;
  int l15 = lane & 15, l4 = lane >> 4;

  const unsigned short* A = ws + OFF_ATT;
  const unsigned short* W = ws + OFF_W + 3u * 65536u;   // Wo
  int i0 = mt * 64 + w * 16;

  f32x4 acc[4] = {};
  for (int ks = 0; ks < 8; ++ks) {
    bf16x8 a = *(const bf16x8*)(A + (size_t)(i0 + l15) * 256 + ks * 32 + l4 * 8);
#pragma unroll
    for (int ct = 0; ct < 4; ++ct) {
      bf16x8 bb = *(const bf16x8*)(W + (size_t)(nt * 64 + ct * 16 + l15) * 256 + ks * 32 + l4 * 8);
      acc[ct] = __builtin_amdgcn_mfma_f32_16x16x32_bf16(a, bb, acc[ct], 0, 0, 0);
    }
  }
#pragma unroll
  for (int ct = 0; ct < 4; ++ct)
#pragma unroll
    for (int r = 0; r < 4; ++r)
      out[(size_t)(i0 + l4 * 4 + r) * 256 + nt * 64 + ct * 16 + l15] = acc[ct][r];
}

extern "C" void kernel_launch(void* const* d_in, const int* in_sizes, int n_in,
                              void* d_out, int out_size, void* d_ws, size_t ws_size,
                              hipStream_t stream) {
  const float* qh = (const float*)d_in[0];
  const float* kh = (const float*)d_in[1];
  const float* amask = (const float*)d_in[2];
  const int* alignm = (const int*)d_in[3];
  const float* Wq = (const float*)d_in[4];
  const float* Wk = (const float*)d_in[5];
  const float* Wv = (const float*)d_in[6];
  const float* Wo = (const float*)d_in[7];
  float* out = (float*)d_out;
  unsigned short* ws = (unsigned short*)d_ws;

  k_convert<<<4352, 256, 0, stream>>>(qh, kh, Wq, Wk, Wv, Wo, ws);
  k_maskprep<<<4096, 256, 0, stream>>>(amask, alignm, ws + OFF_M);
  k_proj<<<1536, 256, 0, stream>>>(ws);
  k_attn<<<512, 256, 0, stream>>>(ws);
  k_oproj<<<512, 256, 0, stream>>>(ws, out);
}

// Round 6
// 152.814 us; speedup vs baseline: 1.4098x; 1.0007x over previous
//
#include <hip/hip_runtime.h>

#define NEGF -3.402823466e38f
#define MASKED_F -3.38953139e38f   // bf16 0xFF7F sentinel, most-negative finite bf16
#define LOG2E 1.44269504088896f

typedef __attribute__((ext_vector_type(8))) short bf16x8;
typedef __attribute__((ext_vector_type(4))) float f32x4;
typedef __attribute__((ext_vector_type(4))) unsigned short u16x4;

__device__ __forceinline__ unsigned short f2bf(float f) {
  unsigned u = __builtin_bit_cast(unsigned, f);
  u += 0x7fffu + ((u >> 16) & 1u);
  return (unsigned short)(u >> 16);
}

#define GLOAD_LDS16(gsrc, ldst)                                                     \
  __builtin_amdgcn_global_load_lds(                                                 \
      (const __attribute__((address_space(1))) void*)(gsrc),                        \
      (__attribute__((address_space(3))) void*)(ldst), 16, 0, 0)

// ws layout in ushort units
#define OFF_QH  0u
#define OFF_KH  2097152u
#define OFF_W   4194304u      // 4 x 65536 (Wq,Wk,Wv,Wo)
#define OFF_QP  4456448u      // [B,H,S,D] bf16, pre-scaled by log2e/8
#define OFF_KP  6553600u      // [B,H,S,D] bf16
#define OFF_VT  8650752u      // [B,H,D,S] bf16 (V transposed)
#define OFF_ATT 10747904u     // [B,S,256] bf16
#define OFF_M   12845056u     // [B][128][32][64][16] bf16 fragment-ordered mask*log2e (32 MB)
#define USHORT_USED 29622272u // end of OFF_M region

// ---------------- f32 -> bf16 conversion of inputs ----------------
__global__ __launch_bounds__(256) void k_convert(
    const float* __restrict__ qh, const float* __restrict__ kh,
    const float* __restrict__ w0, const float* __restrict__ w1,
    const float* __restrict__ w2, const float* __restrict__ w3,
    unsigned short* __restrict__ dst) {
  int v = blockIdx.x * 256 + threadIdx.x;   // vector-of-4 index
  const float* src;
  if (v < 524288)       src = qh + (size_t)v * 4;
  else if (v < 1048576) src = kh + ((size_t)v - 524288) * 4;
  else {
    int t = v - 1048576;                    // 0 .. 65535
    int which = t >> 14;
    const float* w = (which == 0) ? w0 : (which == 1) ? w1 : (which == 2) ? w2 : w3;
    src = w + (size_t)(t & 16383) * 4;
  }
  f32x4 x = *(const f32x4*)src;
  u16x4 o;
  o[0] = f2bf(x[0]); o[1] = f2bf(x[1]); o[2] = f2bf(x[2]); o[3] = f2bf(x[3]);
  *(u16x4*)(dst + (size_t)v * 4) = o;
}

// ---------------- combined-mask prepass (values pre-scaled by log2e) ----------------
__global__ __launch_bounds__(256) void k_maskprep(const float* __restrict__ am,
    const int* __restrict__ al, unsigned short* __restrict__ M) {
  __shared__ float L[64 * 65];
  int bid = blockIdx.x;
  int b = bid >> 10, q64 = (bid >> 5) & 31, k64 = bid & 31;
  int t = threadIdx.x, c = t & 63, rg = t >> 6;

  const float* amb = am + ((size_t)b * 2048 + q64 * 64) * 2048 + k64 * 64;
#pragma unroll
  for (int i = 0; i < 16; ++i) {
    int row = i * 4 + rg;
    L[row * 65 + c] = amb[(size_t)row * 2048 + c] * LOG2E;
  }
  __syncthreads();
  const int* alb = al + ((size_t)b * 2048 + k64 * 64) * 2048 + q64 * 64;
#pragma unroll
  for (int i = 0; i < 16; ++i) {
    int kr = i * 4 + rg;
    if (alb[(size_t)kr * 2048 + c] == 0) L[c * 65 + kr] = MASKED_F;
  }
  __syncthreads();
  int w = t >> 6, lane = t & 63, l15 = lane & 15, l4 = lane >> 4;
  unsigned short* outp = M + ((((size_t)(b * 128 + q64 * 4 + w)) * 32 + k64) * 64 + lane) * 16;
#pragma unroll
  for (int kt = 0; kt < 4; ++kt) {
    u16x4 o;
#pragma unroll
    for (int r = 0; r < 4; ++r)
      o[r] = f2bf(L[(w * 16 + l4 * 4 + r) * 65 + kt * 16 + l15]);
    *(u16x4*)(outp + kt * 4) = o;
  }
}

// ---------------- QKV projections ----------------
__global__ __launch_bounds__(256) void k_proj(unsigned short* __restrict__ ws) {
  int bid = blockIdx.x;
  int mat = bid / 512;            // 0=Q 1=K 2=V
  int rem = bid - mat * 512;
  int mt = rem >> 2, nt = rem & 3;
  int tid = threadIdx.x, w = tid >> 6, lane = tid & 63;
  int l15 = lane & 15, l4 = lane >> 4;

  const unsigned short* X = ws + (mat == 0 ? OFF_QH : OFF_KH);
  const unsigned short* W = ws + OFF_W + (size_t)mat * 65536;

  int i0 = mt * 64 + w * 16;
  int arow = i0 + l15;
  int koff = l4 * 8;

  f32x4 acc[4] = {};
  for (int ks = 0; ks < 8; ++ks) {
    bf16x8 a = *(const bf16x8*)(X + (size_t)arow * 256 + ks * 32 + koff);
#pragma unroll
    for (int ct = 0; ct < 4; ++ct) {
      bf16x8 bb = *(const bf16x8*)(W + (size_t)(nt * 64 + ct * 16 + l15) * 256 + ks * 32 + koff);
      acc[ct] = __builtin_amdgcn_mfma_f32_16x16x32_bf16(a, bb, acc[ct], 0, 0, 0);
    }
  }

  unsigned short* Qp = ws + OFF_QP;
  unsigned short* Kp = ws + OFF_KP;
  unsigned short* Vt = ws + OFF_VT;
  int rbase = i0 + l4 * 4;
#pragma unroll
  for (int ct = 0; ct < 4; ++ct) {
#pragma unroll
    for (int r = 0; r < 4; ++r) {
      int row = rbase + r;
      int b = row >> 11, s = row & 2047;
      int d = ct * 16 + l15;
      float v = acc[ct][r];
      if (mat == 0)      Qp[((size_t)(b * 4 + nt) * 2048 + s) * 64 + d] = f2bf(v * (0.125f * LOG2E));
      else if (mat == 1) Kp[((size_t)(b * 4 + nt) * 2048 + s) * 64 + d] = f2bf(v);
      else               Vt[((size_t)(b * 4 + nt) * 64 + d) * 2048 + s] = f2bf(v);
    }
  }
}

// ---------------- fused masked flash attention (LDS-staged K/V, K-split) ----------------
// scores are in log2 domain (Q pre-scaled by log2e/8, mask by log2e) -> exp2 softmax.
template <int NS>
__global__ __launch_bounds__(256) void k_attn(unsigned short* __restrict__ ws,
    float* __restrict__ po, float* __restrict__ pm, float* __restrict__ pl) {
  constexpr int LOG = (NS == 4) ? 2 : (NS == 2) ? 1 : 0;
  constexpr int SPAN = 2048 / NS;

  __shared__ __align__(16) unsigned short Kb[2][4096];   // [64 krow][64 d] swizzled
  __shared__ __align__(16) unsigned short Vb[2][4096];   // [64 d][64 k] swizzled
  __shared__ __align__(16) unsigned short plds[4][1024]; // per-wave 16x64 P, swizzled

  int bid = blockIdx.x;
  int sp = bid & (NS - 1);
  int qt = (bid >> LOG) & 31;
  int bh = bid >> (LOG + 5);
  int b = bh >> 2, h = bh & 3;
  int tid = threadIdx.x, w = tid >> 6, lane = tid & 63;
  int l15 = lane & 15, l4 = lane >> 4;
  int q0 = qt * 64 + w * 16;

  const unsigned short* Qp = ws + OFF_QP;
  const unsigned short* Kp = ws + OFF_KP + (size_t)bh * 2048 * 64;
  const unsigned short* Vt = ws + OFF_VT + (size_t)bh * 64 * 2048;
  const unsigned short* Mw = ws + OFF_M +
      (((size_t)(b * 128 + qt * 4 + w)) * 32) * 1024 + (size_t)lane * 16;

  // staging geometry: lane i covers row (c*8 + i>>3), global col chunk (i&7)^(i>>3)
  int srow = lane >> 3;
  int scol = ((lane & 7) ^ srow) * 8;
  int c0 = w * 2;

  bf16x8 qf0 = *(const bf16x8*)(Qp + ((size_t)bh * 2048 + q0 + l15) * 64 + l4 * 8);
  bf16x8 qf1 = *(const bf16x8*)(Qp + ((size_t)bh * 2048 + q0 + l15) * 64 + 32 + l4 * 8);

  f32x4 o[4] = {};
  float mrun[4] = {-__builtin_inff(), -__builtin_inff(), -__builtin_inff(), -__builtin_inff()};
  float lrun[4] = {0.f, 0.f, 0.f, 0.f};

  int kk0 = sp * SPAN;
  // prologue: stage tile kk0 into buffer 0
#pragma unroll
  for (int c2 = 0; c2 < 2; ++c2) {
    int c = c0 + c2;
    GLOAD_LDS16(Kp + (size_t)(kk0 + c * 8 + srow) * 64 + scol, &Kb[0][c * 512]);
    GLOAD_LDS16(Vt + (size_t)(c * 8 + srow) * 2048 + kk0 + scol, &Vb[0][c * 512]);
  }
  __syncthreads();

  int cur = 0;
  for (int kk = kk0; kk < kk0 + SPAN; kk += 64) {
    // ---- stage next tile into the other buffer ----
    if (kk + 64 < kk0 + SPAN) {
#pragma unroll
      for (int c2 = 0; c2 < 2; ++c2) {
        int c = c0 + c2;
        GLOAD_LDS16(Kp + (size_t)(kk + 64 + c * 8 + srow) * 64 + scol, &Kb[cur ^ 1][c * 512]);
        GLOAD_LDS16(Vt + (size_t)(c * 8 + srow) * 2048 + (kk + 64) + scol, &Vb[cur ^ 1][c * 512]);
      }
    }
    // ---- mask fragment loads (32 B / lane contiguous) ----
    const unsigned short* mp = Mw + ((size_t)(kk >> 6)) * 1024;
    bf16x8 m0 = *(const bf16x8*)mp;
    bf16x8 m1 = *(const bf16x8*)(mp + 8);

    // ---- scores (log2 domain): S = Q @ K^T from LDS ----
    f32x4 sfr[4];
    __builtin_amdgcn_s_setprio(1);
#pragma unroll
    for (int kt = 0; kt < 4; ++kt) {
      int row = kt * 16 + l15;
      int sw = l15 & 7;
      bf16x8 k0 = *(const bf16x8*)&Kb[cur][row * 64 + ((l4 ^ sw) * 8)];
      bf16x8 k1 = *(const bf16x8*)&Kb[cur][row * 64 + (((4 + l4) ^ sw) * 8)];
      f32x4 acc = {};
      acc = __builtin_amdgcn_mfma_f32_16x16x32_bf16(qf0, k0, acc, 0, 0, 0);
      acc = __builtin_amdgcn_mfma_f32_16x16x32_bf16(qf1, k1, acc, 0, 0, 0);
      sfr[kt] = acc;
    }
    __builtin_amdgcn_s_setprio(0);

    // ---- apply combined mask ----
#pragma unroll
    for (int kt = 0; kt < 4; ++kt) {
#pragma unroll
      for (int r = 0; r < 4; ++r) {
        int j = kt * 4 + r;
        unsigned short mu = (unsigned short)(j < 8 ? m0[j] : m1[j & 7]);
        float madd = __builtin_bit_cast(float, (unsigned)mu << 16);
        sfr[kt][r] = fmaxf(sfr[kt][r] + madd, NEGF);
      }
    }
    // ---- online softmax (exp2) ----
    float mnew[4], sfac[4];
#pragma unroll
    for (int r = 0; r < 4; ++r) {
      float rm = fmaxf(fmaxf(sfr[0][r], sfr[1][r]), fmaxf(sfr[2][r], sfr[3][r]));
      rm = fmaxf(rm, __shfl_xor(rm, 1));
      rm = fmaxf(rm, __shfl_xor(rm, 2));
      rm = fmaxf(rm, __shfl_xor(rm, 4));
      rm = fmaxf(rm, __shfl_xor(rm, 8));
      mnew[r] = fmaxf(mrun[r], rm);
      sfac[r] = exp2f(mrun[r] - mnew[r]);
      mrun[r] = mnew[r];
    }
#pragma unroll
    for (int kt = 0; kt < 4; ++kt)
#pragma unroll
      for (int r = 0; r < 4; ++r)
        sfr[kt][r] = exp2f(sfr[kt][r] - mnew[r]);
#pragma unroll
    for (int r = 0; r < 4; ++r) {
      float rs = sfr[0][r] + sfr[1][r] + sfr[2][r] + sfr[3][r];
      rs += __shfl_xor(rs, 1);
      rs += __shfl_xor(rs, 2);
      rs += __shfl_xor(rs, 4);
      rs += __shfl_xor(rs, 8);
      lrun[r] = lrun[r] * sfac[r] + rs;
      o[0][r] *= sfac[r]; o[1][r] *= sfac[r]; o[2][r] *= sfac[r]; o[3][r] *= sfac[r];
    }
    // ---- P (C-layout) -> plds (XOR-swizzled) ----
#pragma unroll
    for (int kt = 0; kt < 4; ++kt)
#pragma unroll
      for (int r = 0; r < 4; ++r) {
        int prow = l4 * 4 + r;
        int pcol = kt * 16 + l15;
        plds[w][prow * 64 + (((pcol >> 3) ^ (prow & 7)) << 3) + (pcol & 7)] = f2bf(sfr[kt][r]);
      }
    // ---- PV: O += P @ V from LDS ----
    __builtin_amdgcn_s_setprio(1);
#pragma unroll
    for (int ks = 0; ks < 2; ++ks) {
      int chnk = ks * 4 + l4;
      bf16x8 pa = *(const bf16x8*)&plds[w][l15 * 64 + ((chnk ^ (l15 & 7)) << 3)];
#pragma unroll
      for (int dt = 0; dt < 4; ++dt) {
        int row = dt * 16 + l15;
        bf16x8 vf = *(const bf16x8*)&Vb[cur][row * 64 + (((ks * 4 + l4) ^ (l15 & 7)) * 8)];
        o[dt] = __builtin_amdgcn_mfma_f32_16x16x32_bf16(pa, vf, o[dt], 0, 0, 0);
      }
    }
    __builtin_amdgcn_s_setprio(0);

    __syncthreads();   // drains vmcnt (stage done) + guards buffer swap
    cur ^= 1;
  }

  if constexpr (NS == 1) {
    unsigned short* attnb = ws + OFF_ATT;
#pragma unroll
    for (int r = 0; r < 4; ++r) {
      float inv = 1.0f / lrun[r];
      int qrow = q0 + l4 * 4 + r;
#pragma unroll
      for (int dt = 0; dt < 4; ++dt)
        attnb[(size_t)(b * 2048 + qrow) * 256 + h * 64 + dt * 16 + l15] = f2bf(o[dt][r] * inv);
    }
  } else {
    float* pob = po + (((size_t)sp * 16 + bh) * 2048) * 64;
#pragma unroll
    for (int r = 0; r < 4; ++r) {
      int qrow = q0 + l4 * 4 + r;
#pragma unroll
      for (int dt = 0; dt < 4; ++dt)
        pob[(size_t)qrow * 64 + dt * 16 + l15] = o[dt][r];
      if (l15 == 0) {
        pm[(size_t)sp * 32768 + bh * 2048 + qrow] = mrun[r];
        pl[(size_t)sp * 32768 + bh * 2048 + qrow] = lrun[r];
      }
    }
  }
}

// ---------------- combine K-splits (log2 domain weights) ----------------
template <int NS>
__global__ __launch_bounds__(256) void k_combine(const float* __restrict__ po,
    const float* __restrict__ pm, const float* __restrict__ pl,
    unsigned short* __restrict__ attnb) {
  int t = blockIdx.x * 256 + threadIdx.x;
  int d = t & 63;
  int row = t >> 6;                 // bh*2048 + qrow, 0..32767

  float m[NS], l[NS];
  float M = -__builtin_inff();
#pragma unroll
  for (int sp = 0; sp < NS; ++sp) {
    m[sp] = pm[(size_t)sp * 32768 + row];
    l[sp] = pl[(size_t)sp * 32768 + row];
    M = fmaxf(M, m[sp]);
  }
  float denom = 0.f, acc = 0.f;
#pragma unroll
  for (int sp = 0; sp < NS; ++sp) {
    float wgt = exp2f(m[sp] - M);
    denom += l[sp] * wgt;
    acc += po[((size_t)sp * 32768 + row) * 64 + d] * wgt;
  }
  float val = acc / denom;
  int bh = row >> 11, qrow = row & 2047;
  int b = bh >> 2, h = bh & 3;
  attnb[((size_t)(b * 2048 + qrow)) * 256 + h * 64 + d] = f2bf(val);
}

// ---------------- output projection ----------------
__global__ __launch_bounds__(256) void k_oproj(const unsigned short* __restrict__ ws,
                                               float* __restrict__ out) {
  int bid = blockIdx.x;
  int mt = bid >> 2, nt = bid & 3;
  int tid = threadIdx.x, w = tid >> 6, lane = tid & 63;
  int l15 = lane & 15, l4 = lane >> 4;

  const unsigned short* A = ws + OFF_ATT;
  const unsigned short* W = ws + OFF_W + 3u * 65536u;   // Wo
  int i0 = mt * 64 + w * 16;

  f32x4 acc[4] = {};
  for (int ks = 0; ks < 8; ++ks) {
    bf16x8 a = *(const bf16x8*)(A + (size_t)(i0 + l15) * 256 + ks * 32 + l4 * 8);
#pragma unroll
    for (int ct = 0; ct < 4; ++ct) {
      bf16x8 bb = *(const bf16x8*)(W + (size_t)(nt * 64 + ct * 16 + l15) * 256 + ks * 32 + l4 * 8);
      acc[ct] = __builtin_amdgcn_mfma_f32_16x16x32_bf16(a, bb, acc[ct], 0, 0, 0);
    }
  }
#pragma unroll
  for (int ct = 0; ct < 4; ++ct)
#pragma unroll
    for (int r = 0; r < 4; ++r)
      out[(size_t)(i0 + l4 * 4 + r) * 256 + nt * 64 + ct * 16 + l15] = acc[ct][r];
}

extern "C" void kernel_launch(void* const* d_in, const int* in_sizes, int n_in,
                              void* d_out, int out_size, void* d_ws, size_t ws_size,
                              hipStream_t stream) {
  const float* qh = (const float*)d_in[0];
  const float* kh = (const float*)d_in[1];
  const float* amask = (const float*)d_in[2];
  const int* alignm = (const int*)d_in[3];
  const float* Wq = (const float*)d_in[4];
  const float* Wk = (const float*)d_in[5];
  const float* Wv = (const float*)d_in[6];
  const float* Wo = (const float*)d_in[7];
  float* out = (float*)d_out;
  unsigned short* ws = (unsigned short*)d_ws;

  k_convert<<<4352, 256, 0, stream>>>(qh, kh, Wq, Wk, Wv, Wo, ws);
  k_maskprep<<<4096, 256, 0, stream>>>(amask, alignm, ws + OFF_M);
  k_proj<<<1536, 256, 0, stream>>>(ws);

  // f32 partial buffers after the mask region; NS=2 -> 4 blocks/CU (LDS-exact)
  size_t avail_f = (ws_size > (size_t)USHORT_USED * 2)
                       ? (ws_size - (size_t)USHORT_USED * 2) / 4 : 0;
  auto need = [](int ns) { return (size_t)ns * (2097152 + 65536); };
  int NSv = (avail_f >= need(2)) ? 2 : 1;
  float* po = (float*)(ws + USHORT_USED);
  float* pm = po + (size_t)NSv * 2097152;
  float* pl = pm + (size_t)NSv * 32768;

  if (NSv == 2) {
    k_attn<2><<<1024, 256, 0, stream>>>(ws, po, pm, pl);
    k_combine<2><<<8192, 256, 0, stream>>>(po, pm, pl, ws + OFF_ATT);
  } else {
    k_attn<1><<<512, 256, 0, stream>>>(ws, po, pm, pl);
  }
  k_oproj<<<512, 256, 0, stream>>>(ws, out);
}

// Round 7
// 132.308 us; speedup vs baseline: 1.6283x; 1.1550x over previous
//
#include <hip/hip_runtime.h>

#define NEGF -3.402823466e38f
#define MASKED_F -3.38953139e38f   // bf16 0xFF7F sentinel, most-negative finite bf16
#define LOG2E 1.44269504088896f
#define DEFER_THR 8.0f

typedef __attribute__((ext_vector_type(8))) short bf16x8;
typedef __attribute__((ext_vector_type(4))) float f32x4;
typedef __attribute__((ext_vector_type(4))) unsigned short u16x4;
typedef __attribute__((ext_vector_type(2))) unsigned int u32x2;

__device__ __forceinline__ unsigned short f2bf(float f) {
  unsigned u = __builtin_bit_cast(unsigned, f);
  u += 0x7fffu + ((u >> 16) & 1u);
  return (unsigned short)(u >> 16);
}

#define GLOAD_LDS16(gsrc, ldst)                                                     \
  __builtin_amdgcn_global_load_lds(                                                 \
      (const __attribute__((address_space(1))) void*)(gsrc),                        \
      (__attribute__((address_space(3))) void*)(ldst), 16, 0, 0)

// ws layout in ushort units
#define OFF_QH  0u
#define OFF_KH  2097152u
#define OFF_W   4194304u      // 4 x 65536 (Wq,Wk,Wv,Wo)
#define OFF_QP  4456448u      // [B,H,S,D] bf16, pre-scaled by log2e/8
#define OFF_KP  6553600u      // [B,H,S,D] bf16
#define OFF_VT  8650752u      // [B,H,D,S] bf16 (V transposed)
#define OFF_ATT 10747904u     // [B,S,256] bf16
#define OFF_M   12845056u     // [B][128][32][64][16] bf16 fragment-ordered mask*log2e (32 MB)
#define USHORT_USED 29622272u // end of OFF_M region

// ---------------- f32 -> bf16 conversion of inputs ----------------
__global__ __launch_bounds__(256) void k_convert(
    const float* __restrict__ qh, const float* __restrict__ kh,
    const float* __restrict__ w0, const float* __restrict__ w1,
    const float* __restrict__ w2, const float* __restrict__ w3,
    unsigned short* __restrict__ dst) {
  int v = blockIdx.x * 256 + threadIdx.x;   // vector-of-4 index
  const float* src;
  if (v < 524288)       src = qh + (size_t)v * 4;
  else if (v < 1048576) src = kh + ((size_t)v - 524288) * 4;
  else {
    int t = v - 1048576;                    // 0 .. 65535
    int which = t >> 14;
    const float* w = (which == 0) ? w0 : (which == 1) ? w1 : (which == 2) ? w2 : w3;
    src = w + (size_t)(t & 16383) * 4;
  }
  f32x4 x = *(const f32x4*)src;
  u16x4 o;
  o[0] = f2bf(x[0]); o[1] = f2bf(x[1]); o[2] = f2bf(x[2]); o[3] = f2bf(x[3]);
  *(u16x4*)(dst + (size_t)v * 4) = o;
}

// ---------------- combined-mask prepass (values pre-scaled by log2e) ----------------
// NEW fragment order (swapped-QK layout): j = kt*4+r holds value for
// (q = 16*q16 + (lane&15), k = 64*k64 + kt*16 + (lane>>4)*4 + r)
__global__ __launch_bounds__(256) void k_maskprep(const float* __restrict__ am,
    const int* __restrict__ al, unsigned short* __restrict__ M) {
  __shared__ float L[64 * 65];
  int bid = blockIdx.x;
  int b = bid >> 10, q64 = (bid >> 5) & 31, k64 = bid & 31;
  int t = threadIdx.x, c = t & 63, rg = t >> 6;

  const float* amb = am + ((size_t)b * 2048 + q64 * 64) * 2048 + k64 * 64;
#pragma unroll
  for (int i = 0; i < 16; ++i) {
    int row = i * 4 + rg;
    L[row * 65 + c] = amb[(size_t)row * 2048 + c] * LOG2E;
  }
  __syncthreads();
  const int* alb = al + ((size_t)b * 2048 + k64 * 64) * 2048 + q64 * 64;
#pragma unroll
  for (int i = 0; i < 16; ++i) {
    int kr = i * 4 + rg;
    if (alb[(size_t)kr * 2048 + c] == 0) L[c * 65 + kr] = MASKED_F;
  }
  __syncthreads();
  int w = t >> 6, lane = t & 63, l15 = lane & 15, l4 = lane >> 4;
  unsigned short* outp = M + ((((size_t)(b * 128 + q64 * 4 + w)) * 32 + k64) * 64 + lane) * 16;
#pragma unroll
  for (int kt = 0; kt < 4; ++kt) {
    u16x4 o;
#pragma unroll
    for (int r = 0; r < 4; ++r)
      o[r] = f2bf(L[(w * 16 + l15) * 65 + kt * 16 + l4 * 4 + r]);
    *(u16x4*)(outp + kt * 4) = o;
  }
}

// ---------------- QKV projections ----------------
__global__ __launch_bounds__(256) void k_proj(unsigned short* __restrict__ ws) {
  int bid = blockIdx.x;
  int mat = bid / 512;            // 0=Q 1=K 2=V
  int rem = bid - mat * 512;
  int mt = rem >> 2, nt = rem & 3;
  int tid = threadIdx.x, w = tid >> 6, lane = tid & 63;
  int l15 = lane & 15, l4 = lane >> 4;

  const unsigned short* X = ws + (mat == 0 ? OFF_QH : OFF_KH);
  const unsigned short* W = ws + OFF_W + (size_t)mat * 65536;

  int i0 = mt * 64 + w * 16;
  int arow = i0 + l15;
  int koff = l4 * 8;

  f32x4 acc[4] = {};
  for (int ks = 0; ks < 8; ++ks) {
    bf16x8 a = *(const bf16x8*)(X + (size_t)arow * 256 + ks * 32 + koff);
#pragma unroll
    for (int ct = 0; ct < 4; ++ct) {
      bf16x8 bb = *(const bf16x8*)(W + (size_t)(nt * 64 + ct * 16 + l15) * 256 + ks * 32 + koff);
      acc[ct] = __builtin_amdgcn_mfma_f32_16x16x32_bf16(a, bb, acc[ct], 0, 0, 0);
    }
  }

  unsigned short* Qp = ws + OFF_QP;
  unsigned short* Kp = ws + OFF_KP;
  unsigned short* Vt = ws + OFF_VT;
  int rbase = i0 + l4 * 4;
#pragma unroll
  for (int ct = 0; ct < 4; ++ct) {
#pragma unroll
    for (int r = 0; r < 4; ++r) {
      int row = rbase + r;
      int b = row >> 11, s = row & 2047;
      int d = ct * 16 + l15;
      float v = acc[ct][r];
      if (mat == 0)      Qp[((size_t)(b * 4 + nt) * 2048 + s) * 64 + d] = f2bf(v * (0.125f * LOG2E));
      else if (mat == 1) Kp[((size_t)(b * 4 + nt) * 2048 + s) * 64 + d] = f2bf(v);
      else               Vt[((size_t)(b * 4 + nt) * 64 + d) * 2048 + s] = f2bf(v);
    }
  }
}

// ---------------- fused masked flash attention ----------------
// swapped QK^T: sfr[kt][r] = S[k = kk + kt*16 + l4*4 + r][q = q0 + l15]
// -> softmax state (mrun,lpart) is scalar per lane (one q-row per lane).
template <int NS>
__global__ __launch_bounds__(256) void k_attn(unsigned short* __restrict__ ws,
    float* __restrict__ po, float* __restrict__ pm, float* __restrict__ pl) {
  constexpr int LOG = (NS == 4) ? 2 : (NS == 2) ? 1 : 0;
  constexpr int SPAN = 2048 / NS;

  __shared__ __align__(16) unsigned short Kb[2][4096];   // [64 krow][64 d] swizzled
  __shared__ __align__(16) unsigned short Vb[2][4096];   // [64 d][64 k] swizzled
  __shared__ __align__(16) unsigned short plds[4][1024]; // per-wave 16x64 P, swizzled

  int bid = blockIdx.x;
  int sp = bid & (NS - 1);
  int qt = (bid >> LOG) & 31;
  int bh = bid >> (LOG + 5);
  int b = bh >> 2, h = bh & 3;
  int tid = threadIdx.x, w = tid >> 6, lane = tid & 63;
  int l15 = lane & 15, l4 = lane >> 4;
  int q0 = qt * 64 + w * 16;

  const unsigned short* Qp = ws + OFF_QP;
  const unsigned short* Kp = ws + OFF_KP + (size_t)bh * 2048 * 64;
  const unsigned short* Vt = ws + OFF_VT + (size_t)bh * 64 * 2048;
  const unsigned short* Mw = ws + OFF_M +
      (((size_t)(b * 128 + qt * 4 + w)) * 32) * 1024 + (size_t)lane * 16;

  // staging geometry: lane i covers row (c*8 + i>>3), global col chunk (i&7)^(i>>3)
  int srow = lane >> 3;
  int scol = ((lane & 7) ^ srow) * 8;
  int c0 = w * 2;

  bf16x8 qf0 = *(const bf16x8*)(Qp + ((size_t)bh * 2048 + q0 + l15) * 64 + l4 * 8);
  bf16x8 qf1 = *(const bf16x8*)(Qp + ((size_t)bh * 2048 + q0 + l15) * 64 + 32 + l4 * 8);

  f32x4 o[4] = {};
  float mrun = -__builtin_inff();
  float lpart = 0.f;                // per-lane partial sum (this lane's k-subset of row q=l15)

  int kk0 = sp * SPAN;
#pragma unroll
  for (int c2 = 0; c2 < 2; ++c2) {
    int c = c0 + c2;
    GLOAD_LDS16(Kp + (size_t)(kk0 + c * 8 + srow) * 64 + scol, &Kb[0][c * 512]);
    GLOAD_LDS16(Vt + (size_t)(c * 8 + srow) * 2048 + kk0 + scol, &Vb[0][c * 512]);
  }
  __syncthreads();

  int cur = 0;
  for (int kk = kk0; kk < kk0 + SPAN; kk += 64) {
    if (kk + 64 < kk0 + SPAN) {
#pragma unroll
      for (int c2 = 0; c2 < 2; ++c2) {
        int c = c0 + c2;
        GLOAD_LDS16(Kp + (size_t)(kk + 64 + c * 8 + srow) * 64 + scol, &Kb[cur ^ 1][c * 512]);
        GLOAD_LDS16(Vt + (size_t)(c * 8 + srow) * 2048 + (kk + 64) + scol, &Vb[cur ^ 1][c * 512]);
      }
    }
    const unsigned short* mp = Mw + ((size_t)(kk >> 6)) * 1024;
    bf16x8 m0 = *(const bf16x8*)mp;
    bf16x8 m1 = *(const bf16x8*)(mp + 8);

    // ---- scores (log2 domain, swapped): S^T = K @ Q^T ----
    f32x4 sfr[4];
    __builtin_amdgcn_s_setprio(1);
#pragma unroll
    for (int kt = 0; kt < 4; ++kt) {
      int row = kt * 16 + l15;
      int sw = l15 & 7;
      bf16x8 k0 = *(const bf16x8*)&Kb[cur][row * 64 + ((l4 ^ sw) * 8)];
      bf16x8 k1 = *(const bf16x8*)&Kb[cur][row * 64 + (((4 + l4) ^ sw) * 8)];
      f32x4 acc = {};
      acc = __builtin_amdgcn_mfma_f32_16x16x32_bf16(k0, qf0, acc, 0, 0, 0);
      acc = __builtin_amdgcn_mfma_f32_16x16x32_bf16(k1, qf1, acc, 0, 0, 0);
      sfr[kt] = acc;
    }
    __builtin_amdgcn_s_setprio(0);

    // ---- mask add (no clamp needed: all finite) ----
#pragma unroll
    for (int kt = 0; kt < 4; ++kt)
#pragma unroll
      for (int r = 0; r < 4; ++r) {
        int j = kt * 4 + r;
        unsigned short mu = (unsigned short)(j < 8 ? m0[j] : m1[j & 7]);
        sfr[kt][r] += __builtin_bit_cast(float, (unsigned)mu << 16);
      }

    // ---- per-lane row max (all 16 values belong to row q=l15) ----
    float pmax = sfr[0][0];
#pragma unroll
    for (int kt = 0; kt < 4; ++kt)
#pragma unroll
      for (int r = 0; r < 4; ++r) pmax = fmaxf(pmax, sfr[kt][r]);
    pmax = fmaxf(pmax, __shfl_xor(pmax, 16));
    pmax = fmaxf(pmax, __shfl_xor(pmax, 32));

    // ---- defer-max: rescale only when max grew past threshold ----
    if (__any(pmax > mrun + DEFER_THR)) {
      float mnew = fmaxf(mrun, pmax);
      float sfac = exp2f(mrun - mnew);
      mrun = mnew;
      lpart *= sfac;
#pragma unroll
      for (int r = 0; r < 4; ++r) {
        float sf = __shfl(sfac, l4 * 4 + r);
        o[0][r] *= sf; o[1][r] *= sf; o[2][r] *= sf; o[3][r] *= sf;
      }
    }

    // ---- exp2 + in-lane partial sum ----
    float ls = 0.f;
#pragma unroll
    for (int kt = 0; kt < 4; ++kt)
#pragma unroll
      for (int r = 0; r < 4; ++r) {
        float e = exp2f(sfr[kt][r] - mrun);
        sfr[kt][r] = e;
        ls += e;
      }
    lpart += ls;

    // ---- P^T in-lane -> plds[q][k] via cvt_pk + b64 writes (4 consecutive k/lane/kt) ----
#pragma unroll
    for (int kt = 0; kt < 4; ++kt) {
      unsigned lo, hi;
      asm("v_cvt_pk_bf16_f32 %0, %1, %2" : "=v"(lo) : "v"(sfr[kt][0]), "v"(sfr[kt][1]));
      asm("v_cvt_pk_bf16_f32 %0, %1, %2" : "=v"(hi) : "v"(sfr[kt][2]), "v"(sfr[kt][3]));
      int chunk = kt * 2 + (l4 >> 1);
      int addr = l15 * 64 + (((chunk) ^ (l15 & 7)) << 3) + ((l4 & 1) << 2);
      u32x2 pk; pk[0] = lo; pk[1] = hi;
      *(u32x2*)&plds[w][addr] = pk;
    }

    // ---- PV: O += P @ V from LDS ----
    __builtin_amdgcn_s_setprio(1);
#pragma unroll
    for (int ks = 0; ks < 2; ++ks) {
      int chnk = ks * 4 + l4;
      bf16x8 pa = *(const bf16x8*)&plds[w][l15 * 64 + ((chnk ^ (l15 & 7)) << 3)];
#pragma unroll
      for (int dt = 0; dt < 4; ++dt) {
        int row = dt * 16 + l15;
        bf16x8 vf = *(const bf16x8*)&Vb[cur][row * 64 + (((ks * 4 + l4) ^ (l15 & 7)) * 8)];
        o[dt] = __builtin_amdgcn_mfma_f32_16x16x32_bf16(pa, vf, o[dt], 0, 0, 0);
      }
    }
    __builtin_amdgcn_s_setprio(0);

    __syncthreads();   // drains vmcnt (stage done) + guards buffer swap
    cur ^= 1;
  }

  // ---- epilogue: reduce per-lane partial sums across l4 ----
  float lsum = lpart;
  lsum += __shfl_xor(lsum, 16);
  lsum += __shfl_xor(lsum, 32);

  if constexpr (NS == 1) {
    unsigned short* attnb = ws + OFF_ATT;
#pragma unroll
    for (int r = 0; r < 4; ++r) {
      float inv = 1.0f / __shfl(lsum, l4 * 4 + r);
      int qrow = q0 + l4 * 4 + r;
#pragma unroll
      for (int dt = 0; dt < 4; ++dt)
        attnb[(size_t)(b * 2048 + qrow) * 256 + h * 64 + dt * 16 + l15] = f2bf(o[dt][r] * inv);
    }
  } else {
    float* pob = po + (((size_t)sp * 16 + bh) * 2048) * 64;
#pragma unroll
    for (int r = 0; r < 4; ++r) {
      int qrow = q0 + l4 * 4 + r;
#pragma unroll
      for (int dt = 0; dt < 4; ++dt)
        pob[(size_t)qrow * 64 + dt * 16 + l15] = o[dt][r];
    }
    if (l4 == 0) {
      pm[(size_t)sp * 32768 + bh * 2048 + q0 + l15] = mrun;
      pl[(size_t)sp * 32768 + bh * 2048 + q0 + l15] = lsum;
    }
  }
}

// ---------------- combine K-splits (log2 domain weights) ----------------
template <int NS>
__global__ __launch_bounds__(256) void k_combine(const float* __restrict__ po,
    const float* __restrict__ pm, const float* __restrict__ pl,
    unsigned short* __restrict__ attnb) {
  int t = blockIdx.x * 256 + threadIdx.x;
  int d = t & 63;
  int row = t >> 6;                 // bh*2048 + qrow, 0..32767

  float m[NS], l[NS];
  float M = -__builtin_inff();
#pragma unroll
  for (int sp = 0; sp < NS; ++sp) {
    m[sp] = pm[(size_t)sp * 32768 + row];
    l[sp] = pl[(size_t)sp * 32768 + row];
    M = fmaxf(M, m[sp]);
  }
  float denom = 0.f, acc = 0.f;
#pragma unroll
  for (int sp = 0; sp < NS; ++sp) {
    float wgt = exp2f(m[sp] - M);
    denom += l[sp] * wgt;
    acc += po[((size_t)sp * 32768 + row) * 64 + d] * wgt;
  }
  float val = acc / denom;
  int bh = row >> 11, qrow = row & 2047;
  int b = bh >> 2, h = bh & 3;
  attnb[((size_t)(b * 2048 + qrow)) * 256 + h * 64 + d] = f2bf(val);
}

// ---------------- output projection ----------------
__global__ __launch_bounds__(256) void k_oproj(const unsigned short* __restrict__ ws,
                                               float* __restrict__ out) {
  int bid = blockIdx.x;
  int mt = bid >> 2, nt = bid & 3;
  int tid = threadIdx.x, w = tid >> 6, lane = tid & 63;
  int l15 = lane & 15, l4 = lane >> 4;

  const unsigned short* A = ws + OFF_ATT;
  const unsigned short* W = ws + OFF_W + 3u * 65536u;   // Wo
  int i0 = mt * 64 + w * 16;

  f32x4 acc[4] = {};
  for (int ks = 0; ks < 8; ++ks) {
    bf16x8 a = *(const bf16x8*)(A + (size_t)(i0 + l15) * 256 + ks * 32 + l4 * 8);
#pragma unroll
    for (int ct = 0; ct < 4; ++ct) {
      bf16x8 bb = *(const bf16x8*)(W + (size_t)(nt * 64 + ct * 16 + l15) * 256 + ks * 32 + l4 * 8);
      acc[ct] = __builtin_amdgcn_mfma_f32_16x16x32_bf16(a, bb, acc[ct], 0, 0, 0);
    }
  }
#pragma unroll
  for (int ct = 0; ct < 4; ++ct)
#pragma unroll
    for (int r = 0; r < 4; ++r)
      out[(size_t)(i0 + l4 * 4 + r) * 256 + nt * 64 + ct * 16 + l15] = acc[ct][r];
}

extern "C" void kernel_launch(void* const* d_in, const int* in_sizes, int n_in,
                              void* d_out, int out_size, void* d_ws, size_t ws_size,
                              hipStream_t stream) {
  const float* qh = (const float*)d_in[0];
  const float* kh = (const float*)d_in[1];
  const float* amask = (const float*)d_in[2];
  const int* alignm = (const int*)d_in[3];
  const float* Wq = (const float*)d_in[4];
  const float* Wk = (const float*)d_in[5];
  const float* Wv = (const float*)d_in[6];
  const float* Wo = (const float*)d_in[7];
  float* out = (float*)d_out;
  unsigned short* ws = (unsigned short*)d_ws;

  k_convert<<<4352, 256, 0, stream>>>(qh, kh, Wq, Wk, Wv, Wo, ws);
  k_maskprep<<<4096, 256, 0, stream>>>(amask, alignm, ws + OFF_M);
  k_proj<<<1536, 256, 0, stream>>>(ws);

  size_t avail_f = (ws_size > (size_t)USHORT_USED * 2)
                       ? (ws_size - (size_t)USHORT_USED * 2) / 4 : 0;
  auto need = [](int ns) { return (size_t)ns * (2097152 + 65536); };
  int NSv = (avail_f >= need(2)) ? 2 : 1;
  float* po = (float*)(ws + USHORT_USED);
  float* pm = po + (size_t)NSv * 2097152;
  float* pl = pm + (size_t)NSv * 32768;

  if (NSv == 2) {
    k_attn<2><<<1024, 256, 0, stream>>>(ws, po, pm, pl);
    k_combine<2><<<8192, 256, 0, stream>>>(po, pm, pl, ws + OFF_ATT);
  } else {
    k_attn<1><<<512, 256, 0, stream>>>(ws, po, pm, pl);
  }
  k_oproj<<<512, 256, 0, stream>>>(ws, out);
}

// Round 9
// 130.094 us; speedup vs baseline: 1.6560x; 1.0170x over previous
//
#include <hip/hip_runtime.h>

#define NEGF -3.402823466e38f
#define MASKED_F -3.38953139e38f   // bf16 0xFF7F sentinel, most-negative finite bf16
#define LOG2E 1.44269504088896f
#define DEFER_THR 8.0f

typedef __attribute__((ext_vector_type(8))) short bf16x8;
typedef __attribute__((ext_vector_type(4))) float f32x4;
typedef __attribute__((ext_vector_type(4))) unsigned short u16x4;
typedef __attribute__((ext_vector_type(8))) unsigned short u16x8;
typedef __attribute__((ext_vector_type(4))) int i32x4;
typedef __attribute__((ext_vector_type(2))) unsigned int u32x2;

__device__ __forceinline__ unsigned short f2bf(float f) {
  unsigned u = __builtin_bit_cast(unsigned, f);
  u += 0x7fffu + ((u >> 16) & 1u);
  return (unsigned short)(u >> 16);
}

#define GLOAD_LDS16(gsrc, ldst)                                                     \
  __builtin_amdgcn_global_load_lds(                                                 \
      (const __attribute__((address_space(1))) void*)(gsrc),                        \
      (__attribute__((address_space(3))) void*)(ldst), 16, 0, 0)

// ws layout in ushort units
#define OFF_QH  0u
#define OFF_KH  2097152u
#define OFF_W   4194304u      // 4 x 65536 (Wq,Wk,Wv,Wo)
#define OFF_QP  4456448u      // [B,H,S,D] bf16, pre-scaled by log2e/8
#define OFF_KP  6553600u      // [B,H,S,D] bf16
#define OFF_VT  8650752u      // [B,H,D,S] bf16 (V transposed)
#define OFF_ATT 10747904u     // [B,S,256] bf16
#define OFF_M   12845056u     // [B][128][32][64][16] bf16 fragment-ordered mask*log2e (32 MB)
#define USHORT_USED 29622272u // end of OFF_M region

// ---------------- f32 -> bf16 conversion of inputs ----------------
__global__ __launch_bounds__(256) void k_convert(
    const float* __restrict__ qh, const float* __restrict__ kh,
    const float* __restrict__ w0, const float* __restrict__ w1,
    const float* __restrict__ w2, const float* __restrict__ w3,
    unsigned short* __restrict__ dst) {
  int v = blockIdx.x * 256 + threadIdx.x;   // vector-of-4 index
  const float* src;
  if (v < 524288)       src = qh + (size_t)v * 4;
  else if (v < 1048576) src = kh + ((size_t)v - 524288) * 4;
  else {
    int t = v - 1048576;                    // 0 .. 65535
    int which = t >> 14;
    const float* w = (which == 0) ? w0 : (which == 1) ? w1 : (which == 2) ? w2 : w3;
    src = w + (size_t)(t & 16383) * 4;
  }
  f32x4 x = *(const f32x4*)src;
  u16x4 o;
  o[0] = f2bf(x[0]); o[1] = f2bf(x[1]); o[2] = f2bf(x[2]); o[3] = f2bf(x[3]);
  *(u16x4*)(dst + (size_t)v * 4) = o;
}

// ---------------- combined-mask prepass (vectorized, swapped-QK fragment order) ----------------
// M[b][q16][k64][lane][j], j = kt*4+r holds value for
// (q = 16*q16 + (lane&15), k = 64*k64 + kt*16 + (lane>>4)*4 + r)
// amask: direct f32x4 loads (no transpose needed in this layout);
// align: int4-staged LDS tile [64 k][66 pad] read transposed (<=2-way bank alias).
__global__ __launch_bounds__(256) void k_maskprep(const float* __restrict__ am,
    const int* __restrict__ al, unsigned short* __restrict__ M) {
  __shared__ int A[64][66];
  int bid = blockIdx.x;
  int b = bid >> 10, q64 = (bid >> 5) & 31, k64 = bid & 31;
  int t = threadIdx.x;

  // ---- stage align tile [k][q] via int4 coalesced rows ----
  const int* alb = al + ((size_t)b * 2048 + k64 * 64) * 2048 + q64 * 64;
  int r16 = t >> 4, c4 = (t & 15) * 4;
#pragma unroll
  for (int rd = 0; rd < 4; ++rd) {
    int kr = rd * 16 + r16;
    i32x4 v = *(const i32x4*)(alb + (size_t)kr * 2048 + c4);
    A[kr][c4] = v[0]; A[kr][c4 + 1] = v[1]; A[kr][c4 + 2] = v[2]; A[kr][c4 + 3] = v[3];
  }
  __syncthreads();

  int w = t >> 6, lane = t & 63, l15 = lane & 15, l4 = lane >> 4;
  int q = w * 16 + l15;               // q-column within the 64-wide q-tile
  const float* amq = am + ((size_t)(b * 2048 + q64 * 64 + q)) * 2048 + k64 * 64;
  unsigned short* outp = M + ((((size_t)(b * 128 + q64 * 4 + w)) * 32 + k64) * 64 + lane) * 16;

  u16x8 oA, oB;
#pragma unroll
  for (int kt = 0; kt < 4; ++kt) {
    f32x4 a = *(const f32x4*)(amq + kt * 16 + l4 * 4);
#pragma unroll
    for (int r = 0; r < 4; ++r) {
      float v = a[r] * LOG2E;
      if (A[kt * 16 + l4 * 4 + r][q] == 0) v = MASKED_F;   // FIX: q, not l15
      unsigned short u = f2bf(v);
      if (kt < 2) oA[kt * 4 + r] = u;
      else        oB[(kt - 2) * 4 + r] = u;
    }
  }
  *(u16x8*)outp = oA;
  *(u16x8*)(outp + 8) = oB;
}

// ---------------- QKV projections ----------------
__global__ __launch_bounds__(256) void k_proj(unsigned short* __restrict__ ws) {
  int bid = blockIdx.x;
  int mat = bid / 512;            // 0=Q 1=K 2=V
  int rem = bid - mat * 512;
  int mt = rem >> 2, nt = rem & 3;
  int tid = threadIdx.x, w = tid >> 6, lane = tid & 63;
  int l15 = lane & 15, l4 = lane >> 4;

  const unsigned short* X = ws + (mat == 0 ? OFF_QH : OFF_KH);
  const unsigned short* W = ws + OFF_W + (size_t)mat * 65536;

  int i0 = mt * 64 + w * 16;
  int arow = i0 + l15;
  int koff = l4 * 8;

  f32x4 acc[4] = {};
  for (int ks = 0; ks < 8; ++ks) {
    bf16x8 a = *(const bf16x8*)(X + (size_t)arow * 256 + ks * 32 + koff);
#pragma unroll
    for (int ct = 0; ct < 4; ++ct) {
      bf16x8 bb = *(const bf16x8*)(W + (size_t)(nt * 64 + ct * 16 + l15) * 256 + ks * 32 + koff);
      acc[ct] = __builtin_amdgcn_mfma_f32_16x16x32_bf16(a, bb, acc[ct], 0, 0, 0);
    }
  }

  unsigned short* Qp = ws + OFF_QP;
  unsigned short* Kp = ws + OFF_KP;
  unsigned short* Vt = ws + OFF_VT;
  int rbase = i0 + l4 * 4;
#pragma unroll
  for (int ct = 0; ct < 4; ++ct) {
#pragma unroll
    for (int r = 0; r < 4; ++r) {
      int row = rbase + r;
      int b = row >> 11, s = row & 2047;
      int d = ct * 16 + l15;
      float v = acc[ct][r];
      if (mat == 0)      Qp[((size_t)(b * 4 + nt) * 2048 + s) * 64 + d] = f2bf(v * (0.125f * LOG2E));
      else if (mat == 1) Kp[((size_t)(b * 4 + nt) * 2048 + s) * 64 + d] = f2bf(v);
      else               Vt[((size_t)(b * 4 + nt) * 64 + d) * 2048 + s] = f2bf(v);
    }
  }
}

// ---------------- fused masked flash attention ----------------
// swapped QK^T: sfr[kt][r] = S[k = kk + kt*16 + l4*4 + r][q = q0 + l15]
// -> softmax state (mrun,lpart) is scalar per lane (one q-row per lane).
template <int NS>
__global__ __launch_bounds__(256) void k_attn(unsigned short* __restrict__ ws,
    float* __restrict__ po, float* __restrict__ pm, float* __restrict__ pl) {
  constexpr int LOG = (NS == 4) ? 2 : (NS == 2) ? 1 : 0;
  constexpr int SPAN = 2048 / NS;

  __shared__ __align__(16) unsigned short Kb[2][4096];   // [64 krow][64 d] swizzled
  __shared__ __align__(16) unsigned short Vb[2][4096];   // [64 d][64 k] swizzled
  __shared__ __align__(16) unsigned short plds[4][1024]; // per-wave 16x64 P, swizzled

  int bid = blockIdx.x;
  int sp = bid & (NS - 1);
  int qt = (bid >> LOG) & 31;
  int bh = bid >> (LOG + 5);
  int b = bh >> 2, h = bh & 3;
  int tid = threadIdx.x, w = tid >> 6, lane = tid & 63;
  int l15 = lane & 15, l4 = lane >> 4;
  int q0 = qt * 64 + w * 16;

  const unsigned short* Qp = ws + OFF_QP;
  const unsigned short* Kp = ws + OFF_KP + (size_t)bh * 2048 * 64;
  const unsigned short* Vt = ws + OFF_VT + (size_t)bh * 64 * 2048;
  const unsigned short* Mw = ws + OFF_M +
      (((size_t)(b * 128 + qt * 4 + w)) * 32) * 1024 + (size_t)lane * 16;

  // staging geometry: lane i covers row (c*8 + i>>3), global col chunk (i&7)^(i>>3)
  int srow = lane >> 3;
  int scol = ((lane & 7) ^ srow) * 8;
  int c0 = w * 2;

  bf16x8 qf0 = *(const bf16x8*)(Qp + ((size_t)bh * 2048 + q0 + l15) * 64 + l4 * 8);
  bf16x8 qf1 = *(const bf16x8*)(Qp + ((size_t)bh * 2048 + q0 + l15) * 64 + 32 + l4 * 8);

  f32x4 o[4] = {};
  float mrun = -__builtin_inff();
  float lpart = 0.f;                // per-lane partial sum (this lane's k-subset of row q=l15)

  int kk0 = sp * SPAN;
#pragma unroll
  for (int c2 = 0; c2 < 2; ++c2) {
    int c = c0 + c2;
    GLOAD_LDS16(Kp + (size_t)(kk0 + c * 8 + srow) * 64 + scol, &Kb[0][c * 512]);
    GLOAD_LDS16(Vt + (size_t)(c * 8 + srow) * 2048 + kk0 + scol, &Vb[0][c * 512]);
  }
  __syncthreads();

  int cur = 0;
  for (int kk = kk0; kk < kk0 + SPAN; kk += 64) {
    if (kk + 64 < kk0 + SPAN) {
#pragma unroll
      for (int c2 = 0; c2 < 2; ++c2) {
        int c = c0 + c2;
        GLOAD_LDS16(Kp + (size_t)(kk + 64 + c * 8 + srow) * 64 + scol, &Kb[cur ^ 1][c * 512]);
        GLOAD_LDS16(Vt + (size_t)(c * 8 + srow) * 2048 + (kk + 64) + scol, &Vb[cur ^ 1][c * 512]);
      }
    }
    const unsigned short* mp = Mw + ((size_t)(kk >> 6)) * 1024;
    bf16x8 m0 = *(const bf16x8*)mp;
    bf16x8 m1 = *(const bf16x8*)(mp + 8);

    // ---- scores (log2 domain, swapped): S^T = K @ Q^T ----
    f32x4 sfr[4];
    __builtin_amdgcn_s_setprio(1);
#pragma unroll
    for (int kt = 0; kt < 4; ++kt) {
      int row = kt * 16 + l15;
      int sw = l15 & 7;
      bf16x8 k0 = *(const bf16x8*)&Kb[cur][row * 64 + ((l4 ^ sw) * 8)];
      bf16x8 k1 = *(const bf16x8*)&Kb[cur][row * 64 + (((4 + l4) ^ sw) * 8)];
      f32x4 acc = {};
      acc = __builtin_amdgcn_mfma_f32_16x16x32_bf16(k0, qf0, acc, 0, 0, 0);
      acc = __builtin_amdgcn_mfma_f32_16x16x32_bf16(k1, qf1, acc, 0, 0, 0);
      sfr[kt] = acc;
    }
    __builtin_amdgcn_s_setprio(0);

    // ---- mask add (no clamp needed: all finite) ----
#pragma unroll
    for (int kt = 0; kt < 4; ++kt)
#pragma unroll
      for (int r = 0; r < 4; ++r) {
        int j = kt * 4 + r;
        unsigned short mu = (unsigned short)(j < 8 ? m0[j] : m1[j & 7]);
        sfr[kt][r] += __builtin_bit_cast(float, (unsigned)mu << 16);
      }

    // ---- per-lane row max (all 16 values belong to row q=l15) ----
    float pmax = sfr[0][0];
#pragma unroll
    for (int kt = 0; kt < 4; ++kt)
#pragma unroll
      for (int r = 0; r < 4; ++r) pmax = fmaxf(pmax, sfr[kt][r]);
    pmax = fmaxf(pmax, __shfl_xor(pmax, 16));
    pmax = fmaxf(pmax, __shfl_xor(pmax, 32));

    // ---- defer-max: rescale only when max grew past threshold ----
    if (__any(pmax > mrun + DEFER_THR)) {
      float mnew = fmaxf(mrun, pmax);
      float sfac = exp2f(mrun - mnew);
      mrun = mnew;
      lpart *= sfac;
#pragma unroll
      for (int r = 0; r < 4; ++r) {
        float sf = __shfl(sfac, l4 * 4 + r);
        o[0][r] *= sf; o[1][r] *= sf; o[2][r] *= sf; o[3][r] *= sf;
      }
    }

    // ---- exp2 + in-lane partial sum ----
    float ls = 0.f;
#pragma unroll
    for (int kt = 0; kt < 4; ++kt)
#pragma unroll
      for (int r = 0; r < 4; ++r) {
        float e = exp2f(sfr[kt][r] - mrun);
        sfr[kt][r] = e;
        ls += e;
      }
    lpart += ls;

    // ---- P^T in-lane -> plds[q][k] via cvt_pk + b64 writes (4 consecutive k/lane/kt) ----
#pragma unroll
    for (int kt = 0; kt < 4; ++kt) {
      unsigned lo, hi;
      asm("v_cvt_pk_bf16_f32 %0, %1, %2" : "=v"(lo) : "v"(sfr[kt][0]), "v"(sfr[kt][1]));
      asm("v_cvt_pk_bf16_f32 %0, %1, %2" : "=v"(hi) : "v"(sfr[kt][2]), "v"(sfr[kt][3]));
      int chunk = kt * 2 + (l4 >> 1);
      int addr = l15 * 64 + (((chunk) ^ (l15 & 7)) << 3) + ((l4 & 1) << 2);
      u32x2 pk; pk[0] = lo; pk[1] = hi;
      *(u32x2*)&plds[w][addr] = pk;
    }

    // ---- PV: O += P @ V from LDS ----
    __builtin_amdgcn_s_setprio(1);
#pragma unroll
    for (int ks = 0; ks < 2; ++ks) {
      int chnk = ks * 4 + l4;
      bf16x8 pa = *(const bf16x8*)&plds[w][l15 * 64 + ((chnk ^ (l15 & 7)) << 3)];
#pragma unroll
      for (int dt = 0; dt < 4; ++dt) {
        int row = dt * 16 + l15;
        bf16x8 vf = *(const bf16x8*)&Vb[cur][row * 64 + (((ks * 4 + l4) ^ (l15 & 7)) * 8)];
        o[dt] = __builtin_amdgcn_mfma_f32_16x16x32_bf16(pa, vf, o[dt], 0, 0, 0);
      }
    }
    __builtin_amdgcn_s_setprio(0);

    __syncthreads();   // drains vmcnt (stage done) + guards buffer swap
    cur ^= 1;
  }

  // ---- epilogue: reduce per-lane partial sums across l4 ----
  float lsum = lpart;
  lsum += __shfl_xor(lsum, 16);
  lsum += __shfl_xor(lsum, 32);

  if constexpr (NS == 1) {
    unsigned short* attnb = ws + OFF_ATT;
#pragma unroll
    for (int r = 0; r < 4; ++r) {
      float inv = 1.0f / __shfl(lsum, l4 * 4 + r);
      int qrow = q0 + l4 * 4 + r;
#pragma unroll
      for (int dt = 0; dt < 4; ++dt)
        attnb[(size_t)(b * 2048 + qrow) * 256 + h * 64 + dt * 16 + l15] = f2bf(o[dt][r] * inv);
    }
  } else {
    float* pob = po + (((size_t)sp * 16 + bh) * 2048) * 64;
#pragma unroll
    for (int r = 0; r < 4; ++r) {
      int qrow = q0 + l4 * 4 + r;
#pragma unroll
      for (int dt = 0; dt < 4; ++dt)
        pob[(size_t)qrow * 64 + dt * 16 + l15] = o[dt][r];
    }
    if (l4 == 0) {
      pm[(size_t)sp * 32768 + bh * 2048 + q0 + l15] = mrun;
      pl[(size_t)sp * 32768 + bh * 2048 + q0 + l15] = lsum;
    }
  }
}

// ---------------- combine K-splits (log2 domain weights) ----------------
template <int NS>
__global__ __launch_bounds__(256) void k_combine(const float* __restrict__ po,
    const float* __restrict__ pm, const float* __restrict__ pl,
    unsigned short* __restrict__ attnb) {
  int t = blockIdx.x * 256 + threadIdx.x;
  int d = t & 63;
  int row = t >> 6;                 // bh*2048 + qrow, 0..32767

  float m[NS], l[NS];
  float M = -__builtin_inff();
#pragma unroll
  for (int sp = 0; sp < NS; ++sp) {
    m[sp] = pm[(size_t)sp * 32768 + row];
    l[sp] = pl[(size_t)sp * 32768 + row];
    M = fmaxf(M, m[sp]);
  }
  float denom = 0.f, acc = 0.f;
#pragma unroll
  for (int sp = 0; sp < NS; ++sp) {
    float wgt = exp2f(m[sp] - M);
    denom += l[sp] * wgt;
    acc += po[((size_t)sp * 32768 + row) * 64 + d] * wgt;
  }
  float val = acc / denom;
  int bh = row >> 11, qrow = row & 2047;
  int b = bh >> 2, h = bh & 3;
  attnb[((size_t)(b * 2048 + qrow)) * 256 + h * 64 + d] = f2bf(val);
}

// ---------------- output projection ----------------
__global__ __launch_bounds__(256) void k_oproj(const unsigned short* __restrict__ ws,
                                               float* __restrict__ out) {
  int bid = blockIdx.x;
  int mt = bid >> 2, nt = bid & 3;
  int tid = threadIdx.x, w = tid >> 6, lane = tid & 63;
  int l15 = lane & 15, l4 = lane >> 4;

  const unsigned short* A = ws + OFF_ATT;
  const unsigned short* W = ws + OFF_W + 3u * 65536u;   // Wo
  int i0 = mt * 64 + w * 16;

  f32x4 acc[4] = {};
  for (int ks = 0; ks < 8; ++ks) {
    bf16x8 a = *(const bf16x8*)(A + (size_t)(i0 + l15) * 256 + ks * 32 + l4 * 8);
#pragma unroll
    for (int ct = 0; ct < 4; ++ct) {
      bf16x8 bb = *(const bf16x8*)(W + (size_t)(nt * 64 + ct * 16 + l15) * 256 + ks * 32 + l4 * 8);
      acc[ct] = __builtin_amdgcn_mfma_f32_16x16x32_bf16(a, bb, acc[ct], 0, 0, 0);
    }
  }
#pragma unroll
  for (int ct = 0; ct < 4; ++ct)
#pragma unroll
    for (int r = 0; r < 4; ++r)
      out[(size_t)(i0 + l4 * 4 + r) * 256 + nt * 64 + ct * 16 + l15] = acc[ct][r];
}

extern "C" void kernel_launch(void* const* d_in, const int* in_sizes, int n_in,
                              void* d_out, int out_size, void* d_ws, size_t ws_size,
                              hipStream_t stream) {
  const float* qh = (const float*)d_in[0];
  const float* kh = (const float*)d_in[1];
  const float* amask = (const float*)d_in[2];
  const int* alignm = (const int*)d_in[3];
  const float* Wq = (const float*)d_in[4];
  const float* Wk = (const float*)d_in[5];
  const float* Wv = (const float*)d_in[6];
  const float* Wo = (const float*)d_in[7];
  float* out = (float*)d_out;
  unsigned short* ws = (unsigned short*)d_ws;

  k_convert<<<4352, 256, 0, stream>>>(qh, kh, Wq, Wk, Wv, Wo, ws);
  k_maskprep<<<4096, 256, 0, stream>>>(amask, alignm, ws + OFF_M);
  k_proj<<<1536, 256, 0, stream>>>(ws);

  size_t avail_f = (ws_size > (size_t)USHORT_USED * 2)
                       ? (ws_size - (size_t)USHORT_USED * 2) / 4 : 0;
  auto need = [](int ns) { return (size_t)ns * (2097152 + 65536); };
  int NSv = (avail_f >= need(2)) ? 2 : 1;
  float* po = (float*)(ws + USHORT_USED);
  float* pm = po + (size_t)NSv * 2097152;
  float* pl = pm + (size_t)NSv * 32768;

  if (NSv == 2) {
    k_attn<2><<<1024, 256, 0, stream>>>(ws, po, pm, pl);
    k_combine<2><<<8192, 256, 0, stream>>>(po, pm, pl, ws + OFF_ATT);
  } else {
    k_attn<1><<<512, 256, 0, stream>>>(ws, po, pm, pl);
  }
  k_oproj<<<512, 256, 0, stream>>>(ws, out);
}

// Round 10
// 128.686 us; speedup vs baseline: 1.6742x; 1.0109x over previous
//
#include <hip/hip_runtime.h>

#define NEGF -3.402823466e38f
#define MASKED_F -3.38953139e38f   // bf16 0xFF7F sentinel, most-negative finite bf16
#define LOG2E 1.44269504088896f
#define DEFER_THR 8.0f

typedef __attribute__((ext_vector_type(8))) short bf16x8;
typedef __attribute__((ext_vector_type(4))) float f32x4;
typedef __attribute__((ext_vector_type(4))) unsigned short u16x4;
typedef __attribute__((ext_vector_type(8))) unsigned short u16x8;
typedef __attribute__((ext_vector_type(4))) int i32x4;
typedef __attribute__((ext_vector_type(2))) unsigned int u32x2;

__device__ __forceinline__ unsigned short f2bf(float f) {
  unsigned u = __builtin_bit_cast(unsigned, f);
  u += 0x7fffu + ((u >> 16) & 1u);
  return (unsigned short)(u >> 16);
}

#define GLOAD_LDS16(gsrc, ldst)                                                     \
  __builtin_amdgcn_global_load_lds(                                                 \
      (const __attribute__((address_space(1))) void*)(gsrc),                        \
      (__attribute__((address_space(3))) void*)(ldst), 16, 0, 0)

// ws layout in ushort units
#define OFF_QH  0u
#define OFF_KH  2097152u
#define OFF_W   4194304u      // 4 x 65536 (Wq,Wk,Wv,Wo)
#define OFF_QP  4456448u      // [B,H,S,D] bf16, pre-scaled by log2e/8
#define OFF_KP  6553600u      // [B,H,S,D] bf16
#define OFF_VT  8650752u      // [B,H,D,S] bf16 (V transposed)
#define OFF_ATT 10747904u     // [B,S,256] bf16
#define OFF_M   12845056u     // [B][128][32][64][16] bf16 fragment-ordered mask*log2e (32 MB)
#define USHORT_USED 29622272u // end of OFF_M region

// ---------------- f32 -> bf16 conversion of inputs ----------------
__global__ __launch_bounds__(256) void k_convert(
    const float* __restrict__ qh, const float* __restrict__ kh,
    const float* __restrict__ w0, const float* __restrict__ w1,
    const float* __restrict__ w2, const float* __restrict__ w3,
    unsigned short* __restrict__ dst) {
  int v = blockIdx.x * 256 + threadIdx.x;   // vector-of-4 index
  const float* src;
  if (v < 524288)       src = qh + (size_t)v * 4;
  else if (v < 1048576) src = kh + ((size_t)v - 524288) * 4;
  else {
    int t = v - 1048576;                    // 0 .. 65535
    int which = t >> 14;
    const float* w = (which == 0) ? w0 : (which == 1) ? w1 : (which == 2) ? w2 : w3;
    src = w + (size_t)(t & 16383) * 4;
  }
  f32x4 x = *(const f32x4*)src;
  u16x4 o;
  o[0] = f2bf(x[0]); o[1] = f2bf(x[1]); o[2] = f2bf(x[2]); o[3] = f2bf(x[3]);
  *(u16x4*)(dst + (size_t)v * 4) = o;
}

// ---------------- combined-mask prepass (byte-LDS transpose, hoisted amask) ----------------
// M[b][q16][k64][lane][j], j = kt*4+r holds value for
// (q = 16*q16 + (lane&15), k = 64*k64 + kt*16 + (lane>>4)*4 + r)
// align staged as packed BYTES (4.4 KB LDS -> 8 blocks/CU); amask loads hoisted
// above the barrier so HBM latency hides under the barrier wait.
__global__ __launch_bounds__(256) void k_maskprep(const float* __restrict__ am,
    const int* __restrict__ al, unsigned short* __restrict__ M) {
  __shared__ unsigned char AT[64][68];   // [k][q] bytes, padded
  int bid = blockIdx.x;
  int b = bid >> 10, q64 = (bid >> 5) & 31, k64 = bid & 31;
  int t = threadIdx.x;

  // ---- stage align tile [k][q] as packed bytes (4 x ds_write_b32 / thread) ----
  const int* alb = al + ((size_t)b * 2048 + k64 * 64) * 2048 + q64 * 64;
  int r16 = t >> 4, c4 = (t & 15) * 4;
#pragma unroll
  for (int rd = 0; rd < 4; ++rd) {
    int kr = rd * 16 + r16;
    i32x4 v = *(const i32x4*)(alb + (size_t)kr * 2048 + c4);
    unsigned pk = ((unsigned)v[0] & 0xffu) | (((unsigned)v[1] & 0xffu) << 8) |
                  (((unsigned)v[2] & 0xffu) << 16) | (((unsigned)v[3] & 0xffu) << 24);
    *(unsigned*)&AT[kr][c4] = pk;
  }

  // ---- hoist amask loads (independent of LDS) ----
  int w = t >> 6, lane = t & 63, l15 = lane & 15, l4 = lane >> 4;
  int q = w * 16 + l15;               // q-column within the 64-wide q-tile
  const float* amq = am + ((size_t)(b * 2048 + q64 * 64 + q)) * 2048 + k64 * 64;
  f32x4 a0 = *(const f32x4*)(amq + 0 * 16 + l4 * 4);
  f32x4 a1 = *(const f32x4*)(amq + 1 * 16 + l4 * 4);
  f32x4 a2 = *(const f32x4*)(amq + 2 * 16 + l4 * 4);
  f32x4 a3 = *(const f32x4*)(amq + 3 * 16 + l4 * 4);

  __syncthreads();

  unsigned short* outp = M + ((((size_t)(b * 128 + q64 * 4 + w)) * 32 + k64) * 64 + lane) * 16;
  u16x8 oA, oB;
#pragma unroll
  for (int kt = 0; kt < 4; ++kt) {
    f32x4 a = (kt == 0) ? a0 : (kt == 1) ? a1 : (kt == 2) ? a2 : a3;
#pragma unroll
    for (int r = 0; r < 4; ++r) {
      float v = a[r] * LOG2E;
      if (AT[kt * 16 + l4 * 4 + r][q] == 0) v = MASKED_F;
      unsigned short u = f2bf(v);
      if (kt < 2) oA[kt * 4 + r] = u;
      else        oB[(kt - 2) * 4 + r] = u;
    }
  }
  *(u16x8*)outp = oA;
  *(u16x8*)(outp + 8) = oB;
}

// ---------------- QKV projections ----------------
__global__ __launch_bounds__(256) void k_proj(unsigned short* __restrict__ ws) {
  int bid = blockIdx.x;
  int mat = bid / 512;            // 0=Q 1=K 2=V
  int rem = bid - mat * 512;
  int mt = rem >> 2, nt = rem & 3;
  int tid = threadIdx.x, w = tid >> 6, lane = tid & 63;
  int l15 = lane & 15, l4 = lane >> 4;

  const unsigned short* X = ws + (mat == 0 ? OFF_QH : OFF_KH);
  const unsigned short* W = ws + OFF_W + (size_t)mat * 65536;

  int i0 = mt * 64 + w * 16;
  int arow = i0 + l15;
  int koff = l4 * 8;

  f32x4 acc[4] = {};
  for (int ks = 0; ks < 8; ++ks) {
    bf16x8 a = *(const bf16x8*)(X + (size_t)arow * 256 + ks * 32 + koff);
#pragma unroll
    for (int ct = 0; ct < 4; ++ct) {
      bf16x8 bb = *(const bf16x8*)(W + (size_t)(nt * 64 + ct * 16 + l15) * 256 + ks * 32 + koff);
      acc[ct] = __builtin_amdgcn_mfma_f32_16x16x32_bf16(a, bb, acc[ct], 0, 0, 0);
    }
  }

  unsigned short* Qp = ws + OFF_QP;
  unsigned short* Kp = ws + OFF_KP;
  unsigned short* Vt = ws + OFF_VT;
  int rbase = i0 + l4 * 4;
#pragma unroll
  for (int ct = 0; ct < 4; ++ct) {
#pragma unroll
    for (int r = 0; r < 4; ++r) {
      int row = rbase + r;
      int b = row >> 11, s = row & 2047;
      int d = ct * 16 + l15;
      float v = acc[ct][r];
      if (mat == 0)      Qp[((size_t)(b * 4 + nt) * 2048 + s) * 64 + d] = f2bf(v * (0.125f * LOG2E));
      else if (mat == 1) Kp[((size_t)(b * 4 + nt) * 2048 + s) * 64 + d] = f2bf(v);
      else               Vt[((size_t)(b * 4 + nt) * 64 + d) * 2048 + s] = f2bf(v);
    }
  }
}

// ---------------- fused masked flash attention ----------------
// swapped QK^T: sfr[kt][r] = S[k = kk + kt*16 + l4*4 + r][q = q0 + l15]
// -> softmax state (mrun,lpart) is scalar per lane (one q-row per lane).
template <int NS>
__global__ __launch_bounds__(256) void k_attn(unsigned short* __restrict__ ws,
    float* __restrict__ po, float* __restrict__ pm, float* __restrict__ pl) {
  constexpr int LOG = (NS == 4) ? 2 : (NS == 2) ? 1 : 0;
  constexpr int SPAN = 2048 / NS;

  __shared__ __align__(16) unsigned short Kb[2][4096];   // [64 krow][64 d] swizzled
  __shared__ __align__(16) unsigned short Vb[2][4096];   // [64 d][64 k] swizzled
  __shared__ __align__(16) unsigned short plds[4][1024]; // per-wave 16x64 P, swizzled

  int bid = blockIdx.x;
  int sp = bid & (NS - 1);
  int qt = (bid >> LOG) & 31;
  int bh = bid >> (LOG + 5);
  int b = bh >> 2, h = bh & 3;
  int tid = threadIdx.x, w = tid >> 6, lane = tid & 63;
  int l15 = lane & 15, l4 = lane >> 4;
  int q0 = qt * 64 + w * 16;

  const unsigned short* Qp = ws + OFF_QP;
  const unsigned short* Kp = ws + OFF_KP + (size_t)bh * 2048 * 64;
  const unsigned short* Vt = ws + OFF_VT + (size_t)bh * 64 * 2048;
  const unsigned short* Mw = ws + OFF_M +
      (((size_t)(b * 128 + qt * 4 + w)) * 32) * 1024 + (size_t)lane * 16;

  // staging geometry: lane i covers row (c*8 + i>>3), global col chunk (i&7)^(i>>3)
  int srow = lane >> 3;
  int scol = ((lane & 7) ^ srow) * 8;
  int c0 = w * 2;

  bf16x8 qf0 = *(const bf16x8*)(Qp + ((size_t)bh * 2048 + q0 + l15) * 64 + l4 * 8);
  bf16x8 qf1 = *(const bf16x8*)(Qp + ((size_t)bh * 2048 + q0 + l15) * 64 + 32 + l4 * 8);

  f32x4 o[4] = {};
  float mrun = -__builtin_inff();
  float lpart = 0.f;                // per-lane partial sum (this lane's k-subset of row q=l15)

  int kk0 = sp * SPAN;
#pragma unroll
  for (int c2 = 0; c2 < 2; ++c2) {
    int c = c0 + c2;
    GLOAD_LDS16(Kp + (size_t)(kk0 + c * 8 + srow) * 64 + scol, &Kb[0][c * 512]);
    GLOAD_LDS16(Vt + (size_t)(c * 8 + srow) * 2048 + kk0 + scol, &Vb[0][c * 512]);
  }
  __syncthreads();

  int cur = 0;
  for (int kk = kk0; kk < kk0 + SPAN; kk += 64) {
    if (kk + 64 < kk0 + SPAN) {
#pragma unroll
      for (int c2 = 0; c2 < 2; ++c2) {
        int c = c0 + c2;
        GLOAD_LDS16(Kp + (size_t)(kk + 64 + c * 8 + srow) * 64 + scol, &Kb[cur ^ 1][c * 512]);
        GLOAD_LDS16(Vt + (size_t)(c * 8 + srow) * 2048 + (kk + 64) + scol, &Vb[cur ^ 1][c * 512]);
      }
    }
    const unsigned short* mp = Mw + ((size_t)(kk >> 6)) * 1024;
    bf16x8 m0 = *(const bf16x8*)mp;
    bf16x8 m1 = *(const bf16x8*)(mp + 8);

    // ---- scores (log2 domain, swapped): S^T = K @ Q^T ----
    f32x4 sfr[4];
    __builtin_amdgcn_s_setprio(1);
#pragma unroll
    for (int kt = 0; kt < 4; ++kt) {
      int row = kt * 16 + l15;
      int sw = l15 & 7;
      bf16x8 k0 = *(const bf16x8*)&Kb[cur][row * 64 + ((l4 ^ sw) * 8)];
      bf16x8 k1 = *(const bf16x8*)&Kb[cur][row * 64 + (((4 + l4) ^ sw) * 8)];
      f32x4 acc = {};
      acc = __builtin_amdgcn_mfma_f32_16x16x32_bf16(k0, qf0, acc, 0, 0, 0);
      acc = __builtin_amdgcn_mfma_f32_16x16x32_bf16(k1, qf1, acc, 0, 0, 0);
      sfr[kt] = acc;
    }
    __builtin_amdgcn_s_setprio(0);

    // ---- mask add (no clamp needed: all finite) ----
#pragma unroll
    for (int kt = 0; kt < 4; ++kt)
#pragma unroll
      for (int r = 0; r < 4; ++r) {
        int j = kt * 4 + r;
        unsigned short mu = (unsigned short)(j < 8 ? m0[j] : m1[j & 7]);
        sfr[kt][r] += __builtin_bit_cast(float, (unsigned)mu << 16);
      }

    // ---- per-lane row max (all 16 values belong to row q=l15) ----
    float pmax = sfr[0][0];
#pragma unroll
    for (int kt = 0; kt < 4; ++kt)
#pragma unroll
      for (int r = 0; r < 4; ++r) pmax = fmaxf(pmax, sfr[kt][r]);
    pmax = fmaxf(pmax, __shfl_xor(pmax, 16));
    pmax = fmaxf(pmax, __shfl_xor(pmax, 32));

    // ---- defer-max: rescale only when max grew past threshold ----
    if (__any(pmax > mrun + DEFER_THR)) {
      float mnew = fmaxf(mrun, pmax);
      float sfac = exp2f(mrun - mnew);
      mrun = mnew;
      lpart *= sfac;
#pragma unroll
      for (int r = 0; r < 4; ++r) {
        float sf = __shfl(sfac, l4 * 4 + r);
        o[0][r] *= sf; o[1][r] *= sf; o[2][r] *= sf; o[3][r] *= sf;
      }
    }

    // ---- exp2 + in-lane partial sum ----
    float ls = 0.f;
#pragma unroll
    for (int kt = 0; kt < 4; ++kt)
#pragma unroll
      for (int r = 0; r < 4; ++r) {
        float e = exp2f(sfr[kt][r] - mrun);
        sfr[kt][r] = e;
        ls += e;
      }
    lpart += ls;

    // ---- P^T in-lane -> plds[q][k] via cvt_pk + b64 writes (4 consecutive k/lane/kt) ----
#pragma unroll
    for (int kt = 0; kt < 4; ++kt) {
      unsigned lo, hi;
      asm("v_cvt_pk_bf16_f32 %0, %1, %2" : "=v"(lo) : "v"(sfr[kt][0]), "v"(sfr[kt][1]));
      asm("v_cvt_pk_bf16_f32 %0, %1, %2" : "=v"(hi) : "v"(sfr[kt][2]), "v"(sfr[kt][3]));
      int chunk = kt * 2 + (l4 >> 1);
      int addr = l15 * 64 + (((chunk) ^ (l15 & 7)) << 3) + ((l4 & 1) << 2);
      u32x2 pk; pk[0] = lo; pk[1] = hi;
      *(u32x2*)&plds[w][addr] = pk;
    }

    // ---- PV: O += P @ V from LDS ----
    __builtin_amdgcn_s_setprio(1);
#pragma unroll
    for (int ks = 0; ks < 2; ++ks) {
      int chnk = ks * 4 + l4;
      bf16x8 pa = *(const bf16x8*)&plds[w][l15 * 64 + ((chnk ^ (l15 & 7)) << 3)];
#pragma unroll
      for (int dt = 0; dt < 4; ++dt) {
        int row = dt * 16 + l15;
        bf16x8 vf = *(const bf16x8*)&Vb[cur][row * 64 + (((ks * 4 + l4) ^ (l15 & 7)) * 8)];
        o[dt] = __builtin_amdgcn_mfma_f32_16x16x32_bf16(pa, vf, o[dt], 0, 0, 0);
      }
    }
    __builtin_amdgcn_s_setprio(0);

    __syncthreads();   // drains vmcnt (stage done) + guards buffer swap
    cur ^= 1;
  }

  // ---- epilogue: reduce per-lane partial sums across l4 ----
  float lsum = lpart;
  lsum += __shfl_xor(lsum, 16);
  lsum += __shfl_xor(lsum, 32);

  if constexpr (NS == 1) {
    unsigned short* attnb = ws + OFF_ATT;
#pragma unroll
    for (int r = 0; r < 4; ++r) {
      float inv = 1.0f / __shfl(lsum, l4 * 4 + r);
      int qrow = q0 + l4 * 4 + r;
#pragma unroll
      for (int dt = 0; dt < 4; ++dt)
        attnb[(size_t)(b * 2048 + qrow) * 256 + h * 64 + dt * 16 + l15] = f2bf(o[dt][r] * inv);
    }
  } else {
    float* pob = po + (((size_t)sp * 16 + bh) * 2048) * 64;
#pragma unroll
    for (int r = 0; r < 4; ++r) {
      int qrow = q0 + l4 * 4 + r;
#pragma unroll
      for (int dt = 0; dt < 4; ++dt)
        pob[(size_t)qrow * 64 + dt * 16 + l15] = o[dt][r];
    }
    if (l4 == 0) {
      pm[(size_t)sp * 32768 + bh * 2048 + q0 + l15] = mrun;
      pl[(size_t)sp * 32768 + bh * 2048 + q0 + l15] = lsum;
    }
  }
}

// ---------------- combine K-splits (log2 domain weights) ----------------
template <int NS>
__global__ __launch_bounds__(256) void k_combine(const float* __restrict__ po,
    const float* __restrict__ pm, const float* __restrict__ pl,
    unsigned short* __restrict__ attnb) {
  int t = blockIdx.x * 256 + threadIdx.x;
  int d = t & 63;
  int row = t >> 6;                 // bh*2048 + qrow, 0..32767

  float m[NS], l[NS];
  float M = -__builtin_inff();
#pragma unroll
  for (int sp = 0; sp < NS; ++sp) {
    m[sp] = pm[(size_t)sp * 32768 + row];
    l[sp] = pl[(size_t)sp * 32768 + row];
    M = fmaxf(M, m[sp]);
  }
  float denom = 0.f, acc = 0.f;
#pragma unroll
  for (int sp = 0; sp < NS; ++sp) {
    float wgt = exp2f(m[sp] - M);
    denom += l[sp] * wgt;
    acc += po[((size_t)sp * 32768 + row) * 64 + d] * wgt;
  }
  float val = acc / denom;
  int bh = row >> 11, qrow = row & 2047;
  int b = bh >> 2, h = bh & 3;
  attnb[((size_t)(b * 2048 + qrow)) * 256 + h * 64 + d] = f2bf(val);
}

// ---------------- output projection ----------------
__global__ __launch_bounds__(256) void k_oproj(const unsigned short* __restrict__ ws,
                                               float* __restrict__ out) {
  int bid = blockIdx.x;
  int mt = bid >> 2, nt = bid & 3;
  int tid = threadIdx.x, w = tid >> 6, lane = tid & 63;
  int l15 = lane & 15, l4 = lane >> 4;

  const unsigned short* A = ws + OFF_ATT;
  const unsigned short* W = ws + OFF_W + 3u * 65536u;   // Wo
  int i0 = mt * 64 + w * 16;

  f32x4 acc[4] = {};
  for (int ks = 0; ks < 8; ++ks) {
    bf16x8 a = *(const bf16x8*)(A + (size_t)(i0 + l15) * 256 + ks * 32 + l4 * 8);
#pragma unroll
    for (int ct = 0; ct < 4; ++ct) {
      bf16x8 bb = *(const bf16x8*)(W + (size_t)(nt * 64 + ct * 16 + l15) * 256 + ks * 32 + l4 * 8);
      acc[ct] = __builtin_amdgcn_mfma_f32_16x16x32_bf16(a, bb, acc[ct], 0, 0, 0);
    }
  }
#pragma unroll
  for (int ct = 0; ct < 4; ++ct)
#pragma unroll
    for (int r = 0; r < 4; ++r)
      out[(size_t)(i0 + l4 * 4 + r) * 256 + nt * 64 + ct * 16 + l15] = acc[ct][r];
}

extern "C" void kernel_launch(void* const* d_in, const int* in_sizes, int n_in,
                              void* d_out, int out_size, void* d_ws, size_t ws_size,
                              hipStream_t stream) {
  const float* qh = (const float*)d_in[0];
  const float* kh = (const float*)d_in[1];
  const float* amask = (const float*)d_in[2];
  const int* alignm = (const int*)d_in[3];
  const float* Wq = (const float*)d_in[4];
  const float* Wk = (const float*)d_in[5];
  const float* Wv = (const float*)d_in[6];
  const float* Wo = (const float*)d_in[7];
  float* out = (float*)d_out;
  unsigned short* ws = (unsigned short*)d_ws;

  k_convert<<<4352, 256, 0, stream>>>(qh, kh, Wq, Wk, Wv, Wo, ws);
  k_maskprep<<<4096, 256, 0, stream>>>(amask, alignm, ws + OFF_M);
  k_proj<<<1536, 256, 0, stream>>>(ws);

  size_t avail_f = (ws_size > (size_t)USHORT_USED * 2)
                       ? (ws_size - (size_t)USHORT_USED * 2) / 4 : 0;
  auto need = [](int ns) { return (size_t)ns * (2097152 + 65536); };
  int NSv = (avail_f >= need(2)) ? 2 : 1;
  float* po = (float*)(ws + USHORT_USED);
  float* pm = po + (size_t)NSv * 2097152;
  float* pl = pm + (size_t)NSv * 32768;

  if (NSv == 2) {
    k_attn<2><<<1024, 256, 0, stream>>>(ws, po, pm, pl);
    k_combine<2><<<8192, 256, 0, stream>>>(po, pm, pl, ws + OFF_ATT);
  } else {
    k_attn<1><<<512, 256, 0, stream>>>(ws, po, pm, pl);
  }
  k_oproj<<<512, 256, 0, stream>>>(ws, out);
}